// Round 10
// baseline (1102.703 us; speedup 1.0000x reference)
//
#include <hip/hip_runtime.h>

#define NN 50000
#define EE 1600000
#define BBATCH 256
#define DD 64

typedef _Float16 f16;
typedef _Float16 f16x4 __attribute__((ext_vector_type(4)));
typedef _Float16 f16x8 __attribute__((ext_vector_type(8)));
typedef float f32x4 __attribute__((ext_vector_type(4)));

#define MFMA16(a,b,c) __builtin_amdgcn_mfma_f32_16x16x32_f16((a),(b),(c),0,0,0)

// ---------------- LDS layouts (in halves) ----------------
// Edge kernel (1024 thr / 16 waves / 4 waves per SIMD): W1 [128][256->264], W2 [128][136],
// W3 [64][136], h 16x[16][72], bias 320 f32.  Total 157952 B (<160 KiB, 1 block/CU).
constexpr int EW1_RL  = 264;
constexpr int EW1_OFF = 0;
constexpr int EW2_OFF = EW1_OFF + 128 * EW1_RL;   // 33792
constexpr int EW3_OFF = EW2_OFF + 128 * 136;      // 51200
constexpr int EH_OFF  = EW3_OFF + 64 * 136;       // 59904
constexpr int EB_OFF  = EH_OFF + 16 * 16 * 72;    // 78336
constexpr int ELDS    = EB_OFF + 640;             // 78976 halves = 157952 B

// Node/global kernel (256 thr / 4 waves).
constexpr int NW1_RL  = 200;
constexpr int NW1_OFF = 0;
constexpr int NW2_OFF = NW1_OFF + 128 * NW1_RL;   // 25600
constexpr int NW3_OFF = NW2_OFF + 128 * 136;      // 43008
constexpr int NH_OFF  = NW3_OFF + 64 * 136;       // 51712
constexpr int NB_OFF  = NH_OFF + 4 * 32 * 136;    // 69120
constexpr int NLDS    = NB_OFF + 640;             // 69760 halves = 139520 B

// ---------------- helpers ----------------
__device__ __forceinline__ f16x8 pack8(const float* __restrict__ p) {
  f32x4 a = *(const f32x4*)p;
  f32x4 b = *(const f32x4*)(p + 4);
  f16x8 r;
  r[0]=(f16)a[0]; r[1]=(f16)a[1]; r[2]=(f16)a[2]; r[3]=(f16)a[3];
  r[4]=(f16)b[0]; r[5]=(f16)b[1]; r[6]=(f16)b[2]; r[7]=(f16)b[3];
  return r;
}
__device__ __forceinline__ f16x8 pack8s(const float* __restrict__ p, float sc) {
  f32x4 a = *(const f32x4*)p;
  f32x4 b = *(const f32x4*)(p + 4);
  a = a * sc; b = b * sc;
  f16x8 r;
  r[0]=(f16)a[0]; r[1]=(f16)a[1]; r[2]=(f16)a[2]; r[3]=(f16)a[3];
  r[4]=(f16)b[0]; r[5]=(f16)b[1]; r[6]=(f16)b[2]; r[7]=(f16)b[3];
  return r;
}
__device__ __forceinline__ f16x8 cvt8(f32x4 a, f32x4 b) {
  f16x8 r;
  r[0]=(f16)a[0]; r[1]=(f16)a[1]; r[2]=(f16)a[2]; r[3]=(f16)a[3];
  r[4]=(f16)b[0]; r[5]=(f16)b[1]; r[6]=(f16)b[2]; r[7]=(f16)b[3];
  return r;
}

// 3-layer MLP core for node/global kernels (4-wave, h [32][136], unswapped; proven).
template<int KSL, int W1RL, int W1O, int W2O, int W3O>
__device__ __forceinline__ void mlp3_core(f16* __restrict__ sm,
    const float* __restrict__ b1l, const float* __restrict__ b2l,
    const float* __restrict__ b3l,
    const f16x8 (&A1)[2][KSL], const int hb, const int r15, const int g,
    f32x4 (&acc3)[2][4])
{
  #pragma unroll
  for (int hh = 0; hh < 2; ++hh) {
    f32x4 acc[2][4];
    #pragma unroll
    for (int nt = 0; nt < 4; ++nt) {
      const float bv = b1l[(hh*4 + nt)*16 + r15];
      acc[0][nt] = (f32x4){bv, bv, bv, bv};
      acc[1][nt] = acc[0][nt];
    }
    #pragma unroll
    for (int s = 0; s < KSL; ++s) {
      #pragma unroll
      for (int nt = 0; nt < 4; ++nt) {
        const f16x8 bf = *(const f16x8*)&sm[W1O + ((hh*4+nt)*16 + r15) * W1RL + s*32 + g*8];
        acc[0][nt] = MFMA16(A1[0][s], bf, acc[0][nt]);
        acc[1][nt] = MFMA16(A1[1][s], bf, acc[1][nt]);
      }
    }
    #pragma unroll
    for (int mt = 0; mt < 2; ++mt)
      #pragma unroll
      for (int nt = 0; nt < 4; ++nt)
        #pragma unroll
        for (int i = 0; i < 4; ++i)
          sm[hb + (mt*16 + g*4 + i)*136 + (hh*4+nt)*16 + r15] =
              (f16)fmaxf(acc[mt][nt][i], 0.f);
  }

  f16x8 A2[2][4];
  #pragma unroll
  for (int mt = 0; mt < 2; ++mt)
    #pragma unroll
    for (int s = 0; s < 4; ++s)
      A2[mt][s] = *(const f16x8*)&sm[hb + (mt*16 + r15)*136 + s*32 + g*8];

  #pragma unroll
  for (int hh = 0; hh < 2; ++hh) {
    f32x4 acc[2][4];
    #pragma unroll
    for (int nt = 0; nt < 4; ++nt) {
      const float bv = b2l[(hh*4 + nt)*16 + r15];
      acc[0][nt] = (f32x4){bv, bv, bv, bv};
      acc[1][nt] = acc[0][nt];
    }
    #pragma unroll
    for (int s = 0; s < 4; ++s) {
      #pragma unroll
      for (int nt = 0; nt < 4; ++nt) {
        const f16x8 bf = *(const f16x8*)&sm[W2O + ((hh*4+nt)*16 + r15)*136 + s*32 + g*8];
        acc[0][nt] = MFMA16(A2[0][s], bf, acc[0][nt]);
        acc[1][nt] = MFMA16(A2[1][s], bf, acc[1][nt]);
      }
    }
    #pragma unroll
    for (int mt = 0; mt < 2; ++mt)
      #pragma unroll
      for (int nt = 0; nt < 4; ++nt)
        #pragma unroll
        for (int i = 0; i < 4; ++i)
          sm[hb + (mt*16 + g*4 + i)*136 + (hh*4+nt)*16 + r15] =
              (f16)fmaxf(acc[mt][nt][i], 0.f);
  }

  f16x8 A3[2][4];
  #pragma unroll
  for (int mt = 0; mt < 2; ++mt)
    #pragma unroll
    for (int s = 0; s < 4; ++s)
      A3[mt][s] = *(const f16x8*)&sm[hb + (mt*16 + r15)*136 + s*32 + g*8];

  #pragma unroll
  for (int nt = 0; nt < 4; ++nt) {
    const float bv = b3l[nt*16 + r15];
    acc3[0][nt] = (f32x4){bv, bv, bv, bv};
    acc3[1][nt] = acc3[0][nt];
  }
  #pragma unroll
  for (int s = 0; s < 4; ++s) {
    #pragma unroll
    for (int nt = 0; nt < 4; ++nt) {
      const f16x8 bf = *(const f16x8*)&sm[W3O + (nt*16 + r15)*136 + s*32 + g*8];
      acc3[0][nt] = MFMA16(A3[0][s], bf, acc3[0][nt]);
      acc3[1][nt] = MFMA16(A3[1][s], bf, acc3[1][nt]);
    }
  }
}

// ---------------- weight prep: all 9 transposes in ONE launch ----------------
__global__ void transpose_all(
    const float* __restrict__ e1, const float* __restrict__ e2, const float* __restrict__ e3,
    const float* __restrict__ n1, const float* __restrict__ n2, const float* __restrict__ n3,
    const float* __restrict__ q1, const float* __restrict__ q2, const float* __restrict__ q3,
    f16* __restrict__ dst) {
  int tid = blockIdx.x * 256 + threadIdx.x;
  const int o1=32768,o2=49152,o3=57344,o4=81920,o5=98304,o6=106496,o7=131072,o8=147456,o9=155648;
  if (tid >= o9) return;
  const float* src; int in, od, rel;
  if      (tid < o1) { src=e1; in=256; od=128; rel=tid;    }
  else if (tid < o2) { src=e2; in=128; od=128; rel=tid-o1; }
  else if (tid < o3) { src=e3; in=128; od=64;  rel=tid-o2; }
  else if (tid < o4) { src=n1; in=192; od=128; rel=tid-o3; }
  else if (tid < o5) { src=n2; in=128; od=128; rel=tid-o4; }
  else if (tid < o6) { src=n3; in=128; od=64;  rel=tid-o5; }
  else if (tid < o7) { src=q1; in=192; od=128; rel=tid-o6; }
  else if (tid < o8) { src=q2; in=128; od=128; rel=tid-o7; }
  else               { src=q3; in=128; od=64;  rel=tid-o8; }
  int o = rel / in, i = rel - o * in;
  dst[tid] = (f16)src[(size_t)i * od + o];
}

// ---------------- f16 copies of x and u ----------------
__global__ void cvt_xu(const float* __restrict__ x, const float* __restrict__ u,
                       f16* __restrict__ xh, f16* __restrict__ uh) {
  const int XT = NN * 64 / 4;
  const int UT = BBATCH * 64 / 4;
  int tid = blockIdx.x * 256 + threadIdx.x;
  for (int i = tid; i < XT; i += gridDim.x * 256) {
    f32x4 v = *(const f32x4*)&x[(size_t)i * 4];
    f16x4 h; h[0]=(f16)v[0]; h[1]=(f16)v[1]; h[2]=(f16)v[2]; h[3]=(f16)v[3];
    *(f16x4*)&xh[(size_t)i * 4] = h;
  }
  if (tid < UT) {
    f32x4 v = *(const f32x4*)&u[(size_t)tid * 4];
    f16x4 h; h[0]=(f16)v[0]; h[1]=(f16)v[1]; h[2]=(f16)v[2]; h[3]=(f16)v[3];
    *(f16x4*)&uh[(size_t)tid * 4] = h;
  }
}

// ---------------- CSR build ----------------
__global__ void count_kernel(const int* __restrict__ ei, int* __restrict__ deg) {
  int tid = blockIdx.x * 256 + threadIdx.x;
  if (tid < EE) atomicAdd(&deg[ei[tid]], 1);
}

__global__ __launch_bounds__(1024) void scan_kernel(const int* __restrict__ deg,
                                                    int* __restrict__ offs,
                                                    int* __restrict__ cursor) {
  const int t = threadIdx.x;
  const int per = (NN + 1023) / 1024;
  const int s0 = t * per;
  int s1 = s0 + per; if (s1 > NN) s1 = NN;
  int sum = 0;
  for (int i = s0; i < s1; ++i) sum += deg[i];
  const int lane = t & 63, wid = t >> 6;
  int v = sum;
  #pragma unroll
  for (int off = 1; off < 64; off <<= 1) {
    int o = __shfl_up(v, off);
    if (lane >= off) v += o;
  }
  __shared__ int wsums[16];
  __shared__ int wexcl[16];
  if (lane == 63) wsums[wid] = v;
  __syncthreads();
  if (t == 0) { int run = 0; for (int k = 0; k < 16; ++k) { wexcl[k] = run; run += wsums[k]; } }
  __syncthreads();
  int run = wexcl[wid] + v - sum;
  for (int i = s0; i < s1; ++i) { int d = deg[i]; offs[i] = run; cursor[i] = run; run += d; }
  if (t == 1023) offs[NN] = run;
}

__global__ void fill_kernel(const int* __restrict__ ei, int* __restrict__ cursor,
                            int* __restrict__ elist) {
  int tid = blockIdx.x * 256 + threadIdx.x;
  if (tid < EE) {
    int r = ei[tid];
    int pos = atomicAdd(&cursor[r], 1);
    elist[pos] = tid;
  }
}

// ---------------- edge MLP: swapped-operand, 1024 thr / 16 waves / 4 waves-per-SIMD ----------------
// Plain __launch_bounds__(1024): block-fit forces VGPR cap 128; kernel uses ~116 -> no spill,
// and 116 <= 128 keeps all 16 waves resident (4/SIMD). (1024,4) empirically capped at 64 -> spill.
__global__ __launch_bounds__(1024) void edge_mlp_kernel(
    const f16* __restrict__ xh, const float* __restrict__ ea,
    const f16* __restrict__ uh, const int* __restrict__ ei,
    const int* __restrict__ batch,
    const f16* __restrict__ w1t, const f16* __restrict__ w2t, const f16* __restrict__ w3t,
    const float* __restrict__ b1, const float* __restrict__ b2, const float* __restrict__ b3,
    float* __restrict__ e_out)
{
  __shared__ __align__(16) f16 sm[ELDS];
  const int t = threadIdx.x;
  for (int c = t; c < 4096; c += 1024) { int r = c >> 5, kc = c & 31;
    *(uint4*)&sm[EW1_OFF + r*EW1_RL + kc*8] = *(const uint4*)&w1t[r*256 + kc*8]; }
  for (int c = t; c < 2048; c += 1024) { int r = c >> 4, kc = c & 15;
    *(uint4*)&sm[EW2_OFF + r*136 + kc*8] = *(const uint4*)&w2t[r*128 + kc*8]; }
  if (t < 1024) { int c = t; int r = c >> 4, kc = c & 15;
    *(uint4*)&sm[EW3_OFF + r*136 + kc*8] = *(const uint4*)&w3t[r*128 + kc*8]; }
  float* bias = (float*)&sm[EB_OFF];
  if (t < 128) { bias[t] = b1[t]; bias[128 + t] = b2[t]; }
  else if (t < 192) { bias[256 + (t - 128)] = b3[t - 128]; }
  __syncthreads();

  const int l = t & 63, w = t >> 6;         // w in 0..15
  const int r15 = l & 15, g = l >> 4;       // r15 = m-lane, g = n-subrow group
  const int hb = EH_OFF + w * (16 * 72);
  const int NT = EE / 512;                  // 3125
  const int stride = gridDim.x;
  const int t0 = blockIdx.x;

  int rC[2], cC[2], bC[2];   // indices for tile T+1
  int rN[2], cN[2], bN[2];   // indices for tile T+2 (arriving)
  f16x8 Bx[2][6];            // next-tile x/u frags in flight (f16, direct frag layout)
  f32x4 Gea[2][2][2];        // next-tile edge_attr in flight (f32)

  auto issueXU = [&](const int (&rr)[2], const int (&cc)[2], const int (&bb)[2]) {
    #pragma unroll
    for (int mt = 0; mt < 2; ++mt) {
      const f16* pr = xh + (size_t)rr[mt] * 64 + g * 8;
      const f16* pc = xh + (size_t)cc[mt] * 64 + g * 8;
      const f16* pu = uh + (size_t)bb[mt] * 64 + g * 8;
      Bx[mt][0] = *(const f16x8*)pr;        Bx[mt][1] = *(const f16x8*)(pr + 32);
      Bx[mt][2] = *(const f16x8*)pc;        Bx[mt][3] = *(const f16x8*)(pc + 32);
      Bx[mt][4] = *(const f16x8*)pu;        Bx[mt][5] = *(const f16x8*)(pu + 32);
    }
  };
  auto issueEA = [&](int tt) {
    #pragma unroll
    for (int mt = 0; mt < 2; ++mt) {
      const float* pe = ea + ((size_t)(tt * 512 + w * 32 + mt * 16 + r15)) * 64 + g * 8;
      #pragma unroll
      for (int ss = 0; ss < 2; ++ss) {
        Gea[mt][ss][0] = *(const f32x4*)(pe + ss * 32);
        Gea[mt][ss][1] = *(const f32x4*)(pe + ss * 32 + 4);
      }
    }
  };

  // prologue
  {
    int rr[2], cc[2], bb[2];
    #pragma unroll
    for (int mt = 0; mt < 2; ++mt) {
      const int eid = t0 * 512 + w * 32 + mt * 16 + r15;
      rr[mt] = ei[eid]; cc[mt] = ei[EE + eid];
    }
    #pragma unroll
    for (int mt = 0; mt < 2; ++mt) bb[mt] = batch[rr[mt]];
    issueXU(rr, cc, bb); issueEA(t0);
    int t1 = t0 + stride; if (t1 >= NT) t1 = t0;
    #pragma unroll
    for (int mt = 0; mt < 2; ++mt) {
      const int eid = t1 * 512 + w * 32 + mt * 16 + r15;
      rC[mt] = ei[eid]; cC[mt] = ei[EE + eid];
    }
    #pragma unroll
    for (int mt = 0; mt < 2; ++mt) bC[mt] = batch[rC[mt]];
  }

  for (int tile = t0; tile < NT; tile += stride) {
    // ---- assemble data frags (B-operand) for THIS tile ----
    f16x8 A[2][8];
    #pragma unroll
    for (int mt = 0; mt < 2; ++mt) {
      A[mt][0] = Bx[mt][0]; A[mt][1] = Bx[mt][1];
      A[mt][2] = Bx[mt][2]; A[mt][3] = Bx[mt][3];
      A[mt][4] = cvt8(Gea[mt][0][0], Gea[mt][0][1]);
      A[mt][5] = cvt8(Gea[mt][1][0], Gea[mt][1][1]);
      A[mt][6] = Bx[mt][4]; A[mt][7] = Bx[mt][5];
    }

    // prefetch ei for T+2 (cheap, long cover)
    int t2 = tile + 2 * stride; if (t2 >= NT) t2 = t0;
    #pragma unroll
    for (int mt = 0; mt < 2; ++mt) {
      const int eid = t2 * 512 + w * 32 + mt * 16 + r15;
      rN[mt] = ei[eid]; cN[mt] = ei[EE + eid];
    }

    // ---- layer 1 (swapped): D1[n1][m], n1=128 (8 a-tiles), K=256 ----
    f32x4 acc1[2][8];
    #pragma unroll
    for (int a = 0; a < 8; ++a) {
      const f32x4 bv = *(const f32x4*)&bias[a*16 + g*4];
      acc1[0][a] = bv; acc1[1][a] = bv;
    }
    #pragma unroll
    for (int s = 0; s < 8; ++s)
      #pragma unroll
      for (int a = 0; a < 8; ++a) {
        const f16x8 wf = *(const f16x8*)&sm[EW1_OFF + (a*16 + r15)*EW1_RL + s*32 + g*8];
        acc1[0][a] = MFMA16(wf, A[0][s], acc1[0][a]);
        acc1[1][a] = MFMA16(wf, A[1][s], acc1[1][a]);
      }

    // batch for T+2 (rN arrived during layer 1)
    #pragma unroll
    for (int mt = 0; mt < 2; ++mt) bN[mt] = batch[rN[mt]];

    // ---- dance 1: packed b64 writes, per (mt, hh) pass -> B2 frags ----
    f16x8 B2[2][4];
    #pragma unroll
    for (int mt = 0; mt < 2; ++mt)
      #pragma unroll
      for (int hh = 0; hh < 2; ++hh) {
        #pragma unroll
        for (int ap = 0; ap < 4; ++ap) {
          const f32x4 v = acc1[mt][hh*4 + ap];
          f16x4 hv;
          hv[0]=(f16)fmaxf(v[0],0.f); hv[1]=(f16)fmaxf(v[1],0.f);
          hv[2]=(f16)fmaxf(v[2],0.f); hv[3]=(f16)fmaxf(v[3],0.f);
          *(f16x4*)&sm[hb + r15*72 + ap*16 + g*4] = hv;
        }
        #pragma unroll
        for (int sl = 0; sl < 2; ++sl)
          B2[mt][hh*2 + sl] = *(const f16x8*)&sm[hb + r15*72 + sl*32 + g*8];
      }

    // issue next tile's x/u loads (covered by layers 2-3)
    int t1 = tile + stride; if (t1 >= NT) t1 = t0;
    issueXU(rC, cC, bC);

    // ---- layer 2 (swapped): n2=128, K=128 ----
    f32x4 acc2[2][8];
    #pragma unroll
    for (int a = 0; a < 8; ++a) {
      const f32x4 bv = *(const f32x4*)&bias[128 + a*16 + g*4];
      acc2[0][a] = bv; acc2[1][a] = bv;
    }
    #pragma unroll
    for (int s = 0; s < 4; ++s)
      #pragma unroll
      for (int a = 0; a < 8; ++a) {
        const f16x8 wf = *(const f16x8*)&sm[EW2_OFF + (a*16 + r15)*136 + s*32 + g*8];
        acc2[0][a] = MFMA16(wf, B2[0][s], acc2[0][a]);
        acc2[1][a] = MFMA16(wf, B2[1][s], acc2[1][a]);
      }

    // ---- dance 2 -> B3 frags ----
    f16x8 B3[2][4];
    #pragma unroll
    for (int mt = 0; mt < 2; ++mt)
      #pragma unroll
      for (int hh = 0; hh < 2; ++hh) {
        #pragma unroll
        for (int ap = 0; ap < 4; ++ap) {
          const f32x4 v = acc2[mt][hh*4 + ap];
          f16x4 hv;
          hv[0]=(f16)fmaxf(v[0],0.f); hv[1]=(f16)fmaxf(v[1],0.f);
          hv[2]=(f16)fmaxf(v[2],0.f); hv[3]=(f16)fmaxf(v[3],0.f);
          *(f16x4*)&sm[hb + r15*72 + ap*16 + g*4] = hv;
        }
        #pragma unroll
        for (int sl = 0; sl < 2; ++sl)
          B3[mt][hh*2 + sl] = *(const f16x8*)&sm[hb + r15*72 + sl*32 + g*8];
      }

    // issue next tile's ea loads (covered by layer 3 + store)
    issueEA(t1);

    // ---- layer 3 (swapped): n3=64, K=128 ----
    f32x4 acc3[2][4];
    #pragma unroll
    for (int a = 0; a < 4; ++a) {
      const f32x4 bv = *(const f32x4*)&bias[256 + a*16 + g*4];
      acc3[0][a] = bv; acc3[1][a] = bv;
    }
    #pragma unroll
    for (int s = 0; s < 4; ++s)
      #pragma unroll
      for (int a = 0; a < 4; ++a) {
        const f16x8 wf = *(const f16x8*)&sm[EW3_OFF + (a*16 + r15)*136 + s*32 + g*8];
        acc3[0][a] = MFMA16(wf, B3[0][s], acc3[0][a]);
        acc3[1][a] = MFMA16(wf, B3[1][s], acc3[1][a]);
      }

    // ---- epilogue: vector stores (lane holds e[m][16a+4g .. +3]) ----
    const int base = tile * 512 + w * 32;
    #pragma unroll
    for (int mt = 0; mt < 2; ++mt) {
      const int m = base + mt * 16 + r15;
      #pragma unroll
      for (int a = 0; a < 4; ++a)
        *(f32x4*)&e_out[(size_t)m * 64 + a*16 + g*4] = acc3[mt][a];
    }

    #pragma unroll
    for (int mt = 0; mt < 2; ++mt) { rC[mt] = rN[mt]; cC[mt] = cN[mt]; bC[mt] = bN[mt]; }
  }
}

// ---------------- n_agg sums via CSR gather (8-deep ILP) ----------------
__global__ void nsum_kernel(const float* __restrict__ e_src, const int* __restrict__ offs,
                            const int* __restrict__ elist, float* __restrict__ n_sum) {
  const int l = threadIdx.x & 63;
  const int wid = (blockIdx.x * blockDim.x + threadIdx.x) >> 6;
  const int nw = (gridDim.x * blockDim.x) >> 6;
  for (int node = wid; node < NN; node += nw) {
    const int s = offs[node], e = offs[node + 1];
    float acc = 0.f;
    int j = s;
    for (; j + 8 <= e; j += 8) {
      float v0 = e_src[(size_t)elist[j]   * 64 + l];
      float v1 = e_src[(size_t)elist[j+1] * 64 + l];
      float v2 = e_src[(size_t)elist[j+2] * 64 + l];
      float v3 = e_src[(size_t)elist[j+3] * 64 + l];
      float v4 = e_src[(size_t)elist[j+4] * 64 + l];
      float v5 = e_src[(size_t)elist[j+5] * 64 + l];
      float v6 = e_src[(size_t)elist[j+6] * 64 + l];
      float v7 = e_src[(size_t)elist[j+7] * 64 + l];
      acc += ((v0 + v1) + (v2 + v3)) + ((v4 + v5) + (v6 + v7));
    }
    for (; j < e; ++j) acc += e_src[(size_t)elist[j] * 64 + l];
    n_sum[(size_t)node * 64 + l] = acc;
  }
}

// ---------------- node MLP (persistent: stage weights once, loop tiles) ----------------
__global__ __launch_bounds__(256, 1) void node_mlp_kernel(
    const float* __restrict__ x, const float* __restrict__ u,
    const int* __restrict__ batch, const float* __restrict__ n_sum,
    const int* __restrict__ deg,
    const f16* __restrict__ w1t, const f16* __restrict__ w2t, const f16* __restrict__ w3t,
    const float* __restrict__ b1, const float* __restrict__ b2, const float* __restrict__ b3,
    float* __restrict__ xn_out)
{
  __shared__ __align__(16) f16 sm[NLDS];
  const int t = threadIdx.x;
  for (int c = t; c < 3072; c += 256) { int r = c / 24, kc = c - r * 24;
    *(uint4*)&sm[NW1_OFF + r*NW1_RL + kc*8] = *(const uint4*)&w1t[r*192 + kc*8]; }
  for (int c = t; c < 2048; c += 256) { int r = c >> 4, kc = c & 15;
    *(uint4*)&sm[NW2_OFF + r*136 + kc*8] = *(const uint4*)&w2t[r*128 + kc*8]; }
  for (int c = t; c < 1024; c += 256) { int r = c >> 4, kc = c & 15;
    *(uint4*)&sm[NW3_OFF + r*136 + kc*8] = *(const uint4*)&w3t[r*128 + kc*8]; }
  float* bias = (float*)&sm[NB_OFF];
  if (t < 128) { bias[t] = b1[t]; bias[128 + t] = b2[t]; }
  if (t < 64)  { bias[256 + t] = b3[t]; }
  __syncthreads();

  const int l = t & 63, w = t >> 6;
  const int r15 = l & 15, g = l >> 4;
  const int hb = NH_OFF + w * (32 * 136);
  const int NTT = (NN + 127) / 128;   // 391

  for (int tile = blockIdx.x; tile < NTT; tile += gridDim.x) {
    const int base = tile * 128 + w * 32;
    f16x8 A1[2][6];
    #pragma unroll
    for (int mt = 0; mt < 2; ++mt) {
      int raw = base + mt * 16 + r15;
      int node = raw < NN ? raw : NN - 1;
      float inv = 1.0f / fmaxf((float)deg[node], 1.0f);
      const float* sA = n_sum + (size_t)node * 64;
      const float* sB = x + (size_t)node * 64;
      const float* sC = u + (size_t)batch[node] * 64;
      #pragma unroll
      for (int s = 0; s < 6; ++s) {
        const int off = (s & 1) * 32 + g * 8;
        if (s < 2)      A1[mt][s] = pack8s(sA + off, inv);
        else if (s < 4) A1[mt][s] = pack8(sB + off);
        else            A1[mt][s] = pack8(sC + off);
      }
    }
    f32x4 acc3[2][4];
    mlp3_core<6, NW1_RL, NW1_OFF, NW2_OFF, NW3_OFF>(sm, bias, bias + 128, bias + 256,
                                                    A1, hb, r15, g, acc3);
    #pragma unroll
    for (int mt = 0; mt < 2; ++mt)
      #pragma unroll
      for (int nt = 0; nt < 4; ++nt)
        #pragma unroll
        for (int i = 0; i < 4; ++i) {
          const int m = base + mt * 16 + g * 4 + i;
          if (m < NN) xn_out[(size_t)m * 64 + nt * 16 + r15] = acc3[mt][nt][i];
        }
  }
}

// ---------------- batch segment starts ----------------
__global__ void bstart_kernel(const int* __restrict__ batch, int* __restrict__ bstart) {
  int tid = blockIdx.x * 256 + threadIdx.x;
  if (tid >= NN) return;
  int b = batch[tid];
  if (tid == 0) { for (int k = 0; k <= b; ++k) bstart[k] = 0; }
  else { int pb = batch[tid - 1]; for (int k = pb + 1; k <= b; ++k) bstart[k] = tid; }
  if (tid == NN - 1) { for (int k = b + 1; k <= BBATCH; ++k) bstart[k] = NN; }
}

// ---------------- per-batch segmented sums ----------------
__global__ void batch_sum_kernel(const float* __restrict__ xn, const float* __restrict__ n_sum,
                                 const int* __restrict__ deg, const int* __restrict__ bstart,
                                 float* __restrict__ nbsum, float* __restrict__ ebsum,
                                 int* __restrict__ ncnt, int* __restrict__ ecnt) {
  __shared__ float red0[256];
  __shared__ float red1[256];
  __shared__ int   redi[256];
  const int b = blockIdx.x;
  const int s = bstart[b], e = bstart[b + 1];
  const int t = threadIdx.x, c = t & 63, j0 = t >> 6;
  float xs = 0.f, ns = 0.f; int dc = 0;
  for (int j = s + j0; j < e; j += 4) {
    xs += xn[(size_t)j * 64 + c];
    ns += n_sum[(size_t)j * 64 + c];
    if (c == 0) dc += deg[j];
  }
  red0[t] = xs; red1[t] = ns; redi[t] = dc;
  __syncthreads();
  if (t < 128) { red0[t] += red0[t + 128]; red1[t] += red1[t + 128]; redi[t] += redi[t + 128]; }
  __syncthreads();
  if (t < 64) {
    float a0 = red0[t] + red0[t + 64];
    float a1 = red1[t] + red1[t + 64];
    nbsum[b * 64 + t] = a0;
    ebsum[b * 64 + t] = a1;
    if (t == 0) { ncnt[b] = e - s; ecnt[b] = redi[0] + redi[64]; }
  }
}

// ---------------- global MLP ----------------
__global__ __launch_bounds__(256, 1) void global_mlp_kernel(
    const float* __restrict__ u, const float* __restrict__ nbsum,
    const float* __restrict__ ebsum, const int* __restrict__ ncnt,
    const int* __restrict__ ecnt,
    const f16* __restrict__ w1t, const f16* __restrict__ w2t, const f16* __restrict__ w3t,
    const float* __restrict__ b1, const float* __restrict__ b2, const float* __restrict__ b3,
    float* __restrict__ un_out)
{
  __shared__ __align__(16) f16 sm[NLDS];
  const int t = threadIdx.x;
  for (int c = t; c < 3072; c += 256) { int r = c / 24, kc = c - r * 24;
    *(uint4*)&sm[NW1_OFF + r*NW1_RL + kc*8] = *(const uint4*)&w1t[r*192 + kc*8]; }
  for (int c = t; c < 2048; c += 256) { int r = c >> 4, kc = c & 15;
    *(uint4*)&sm[NW2_OFF + r*136 + kc*8] = *(const uint4*)&w2t[r*128 + kc*8]; }
  for (int c = t; c < 1024; c += 256) { int r = c >> 4, kc = c & 15;
    *(uint4*)&sm[NW3_OFF + r*136 + kc*8] = *(const uint4*)&w3t[r*128 + kc*8]; }
  float* bias = (float*)&sm[NB_OFF];
  if (t < 128) { bias[t] = b1[t]; bias[128 + t] = b2[t]; }
  if (t < 64)  { bias[256 + t] = b3[t]; }
  __syncthreads();

  const int l = t & 63, w = t >> 6;
  const int r15 = l & 15, g = l >> 4;
  const int hb = NH_OFF + w * (32 * 136);
  const int base = blockIdx.x * 128 + w * 32;

  f16x8 A1[2][6];
  #pragma unroll
  for (int mt = 0; mt < 2; ++mt) {
    const int r = base + mt * 16 + r15;
    const float invn = 1.0f / fmaxf((float)ncnt[r], 1.0f);
    const float inve = 1.0f / fmaxf((float)ecnt[r], 1.0f);
    const float* sA = u + (size_t)r * 64;
    const float* sB = nbsum + (size_t)r * 64;
    const float* sC = ebsum + (size_t)r * 64;
    #pragma unroll
    for (int s = 0; s < 6; ++s) {
      const int off = (s & 1) * 32 + g * 8;
      if (s < 2)      A1[mt][s] = pack8(sA + off);
      else if (s < 4) A1[mt][s] = pack8s(sB + off, invn);
      else            A1[mt][s] = pack8s(sC + off, inve);
    }
  }
  f32x4 acc3[2][4];
  mlp3_core<6, NW1_RL, NW1_OFF, NW2_OFF, NW3_OFF>(sm, bias, bias + 128, bias + 256,
                                                  A1, hb, r15, g, acc3);
  #pragma unroll
  for (int mt = 0; mt < 2; ++mt)
    #pragma unroll
    for (int nt = 0; nt < 4; ++nt)
      #pragma unroll
      for (int i = 0; i < 4; ++i) {
        const int m = base + mt * 16 + g * 4 + i;
        un_out[(size_t)m * 64 + nt * 16 + r15] = acc3[mt][nt][i];
      }
}

// ---------------- host launcher ----------------
extern "C" void kernel_launch(void* const* d_in, const int* in_sizes, int n_in,
                              void* d_out, int out_size, void* d_ws, size_t ws_size,
                              hipStream_t stream)
{
  (void)in_sizes; (void)n_in; (void)out_size; (void)ws_size;
  const float* x     = (const float*)d_in[0];
  const float* ea    = (const float*)d_in[1];
  const float* u     = (const float*)d_in[2];
  const int*   ei    = (const int*)d_in[3];
  const int*   batch = (const int*)d_in[4];
  const float* ew1 = (const float*)d_in[5];  const float* eb1 = (const float*)d_in[6];
  const float* ew2 = (const float*)d_in[7];  const float* eb2 = (const float*)d_in[8];
  const float* ew3 = (const float*)d_in[9];  const float* eb3 = (const float*)d_in[10];
  const float* nw1 = (const float*)d_in[11]; const float* nb1 = (const float*)d_in[12];
  const float* nw2 = (const float*)d_in[13]; const float* nb2 = (const float*)d_in[14];
  const float* nw3 = (const float*)d_in[15]; const float* nb3 = (const float*)d_in[16];
  const float* gw1 = (const float*)d_in[17]; const float* gb1 = (const float*)d_in[18];
  const float* gw2 = (const float*)d_in[19]; const float* gb2 = (const float*)d_in[20];
  const float* gw3 = (const float*)d_in[21]; const float* gb3 = (const float*)d_in[22];

  float* xn_out = (float*)d_out;
  float* e_out  = xn_out + (size_t)NN * DD;
  float* un_out = e_out + (size_t)EE * DD;

  char* p = (char*)d_ws;
  auto alloc = [&](size_t bytes) -> void* {
    void* r = (void*)p; p += (bytes + 255) & ~(size_t)255; return r;
  };
  // NOTE: 9 weight buffers must stay contiguous in this order (transpose_all writes linearly)
  f16* wtE1 = (f16*)alloc(256 * 128 * 2);
  f16* wtE2 = (f16*)alloc(128 * 128 * 2);
  f16* wtE3 = (f16*)alloc(128 * 64 * 2);
  f16* wtN1 = (f16*)alloc(192 * 128 * 2);
  f16* wtN2 = (f16*)alloc(128 * 128 * 2);
  f16* wtN3 = (f16*)alloc(128 * 64 * 2);
  f16* wtG1 = (f16*)alloc(192 * 128 * 2);
  f16* wtG2 = (f16*)alloc(128 * 128 * 2);
  f16* wtG3 = (f16*)alloc(128 * 64 * 2);
  int* deg    = (int*)alloc((size_t)NN * 4);
  int* offs   = (int*)alloc((size_t)(NN + 1) * 4);
  int* cursor = (int*)alloc((size_t)NN * 4);
  int* elist  = (int*)alloc((size_t)EE * 4);
  int* bstart = (int*)alloc((size_t)(BBATCH + 1) * 4);
  float* nbsum = (float*)alloc((size_t)BBATCH * 64 * 4);
  float* ebsum = (float*)alloc((size_t)BBATCH * 64 * 4);
  int* ncnt = (int*)alloc((size_t)BBATCH * 4);
  int* ecnt = (int*)alloc((size_t)BBATCH * 4);
  float* n_sum = (float*)alloc((size_t)NN * 64 * 4);
  f16* xh = (f16*)alloc((size_t)NN * 64 * 2);
  f16* uh = (f16*)alloc((size_t)BBATCH * 64 * 2);

  transpose_all<<<dim3(608), dim3(256), 0, stream>>>(
      ew1, ew2, ew3, nw1, nw2, nw3, gw1, gw2, gw3, wtE1);
  cvt_xu<<<dim3(1024), dim3(256), 0, stream>>>(x, u, xh, uh);

  hipMemsetAsync(deg, 0, (size_t)NN * 4, stream);
  count_kernel<<<dim3(6250), dim3(256), 0, stream>>>(ei, deg);
  scan_kernel<<<dim3(1), dim3(1024), 0, stream>>>(deg, offs, cursor);
  fill_kernel<<<dim3(6250), dim3(256), 0, stream>>>(ei, cursor, elist);

  edge_mlp_kernel<<<dim3(256), dim3(1024), 0, stream>>>(
      xh, ea, uh, ei, batch, wtE1, wtE2, wtE3, eb1, eb2, eb3, e_out);

  nsum_kernel<<<dim3(4096), dim3(256), 0, stream>>>(e_out, offs, elist, n_sum);

  node_mlp_kernel<<<dim3(128), dim3(256), 0, stream>>>(
      x, u, batch, n_sum, deg, wtN1, wtN2, wtN3, nb1, nb2, nb3, xn_out);

  bstart_kernel<<<dim3((NN + 255) / 256), dim3(256), 0, stream>>>(batch, bstart);
  batch_sum_kernel<<<dim3(BBATCH), dim3(256), 0, stream>>>(
      xn_out, n_sum, deg, bstart, nbsum, ebsum, ncnt, ecnt);

  global_mlp_kernel<<<dim3(2), dim3(256), 0, stream>>>(
      u, nbsum, ebsum, ncnt, ecnt, wtG1, wtG2, wtG3, gb1, gb2, gb3, un_out);
}

// Round 11
// 1088.569 us; speedup vs baseline: 1.0130x; 1.0130x over previous
//
#include <hip/hip_runtime.h>

#define NN 50000
#define EE 1600000
#define BBATCH 256
#define DD 64

typedef _Float16 f16;
typedef _Float16 f16x4 __attribute__((ext_vector_type(4)));
typedef _Float16 f16x8 __attribute__((ext_vector_type(8)));
typedef float f32x4 __attribute__((ext_vector_type(4)));

#define MFMA16(a,b,c) __builtin_amdgcn_mfma_f32_16x16x32_f16((a),(b),(c),0,0,0)

// ---------------- LDS layouts (in halves) ----------------
// Edge kernel (1024 thr / 16 waves / 4 waves per SIMD): W1 [128][256->264], W2 [128][136],
// W3 [64][136], h 16x[16][72], bias 320 f32.  Total 157952 B (<160 KiB, 1 block/CU).
constexpr int EW1_RL  = 264;
constexpr int EW1_OFF = 0;
constexpr int EW2_OFF = EW1_OFF + 128 * EW1_RL;   // 33792
constexpr int EW3_OFF = EW2_OFF + 128 * 136;      // 51200
constexpr int EH_OFF  = EW3_OFF + 64 * 136;       // 59904
constexpr int EB_OFF  = EH_OFF + 16 * 16 * 72;    // 78336
constexpr int ELDS    = EB_OFF + 640;             // 78976 halves = 157952 B

// Node/global kernel (256 thr / 4 waves).
constexpr int NW1_RL  = 200;
constexpr int NW1_OFF = 0;
constexpr int NW2_OFF = NW1_OFF + 128 * NW1_RL;   // 25600
constexpr int NW3_OFF = NW2_OFF + 128 * 136;      // 43008
constexpr int NH_OFF  = NW3_OFF + 64 * 136;       // 51712
constexpr int NB_OFF  = NH_OFF + 4 * 32 * 136;    // 69120
constexpr int NLDS    = NB_OFF + 640;             // 69760 halves = 139520 B

// ---------------- helpers ----------------
__device__ __forceinline__ f16x8 pack8(const float* __restrict__ p) {
  f32x4 a = *(const f32x4*)p;
  f32x4 b = *(const f32x4*)(p + 4);
  f16x8 r;
  r[0]=(f16)a[0]; r[1]=(f16)a[1]; r[2]=(f16)a[2]; r[3]=(f16)a[3];
  r[4]=(f16)b[0]; r[5]=(f16)b[1]; r[6]=(f16)b[2]; r[7]=(f16)b[3];
  return r;
}
__device__ __forceinline__ f16x8 pack8s(const float* __restrict__ p, float sc) {
  f32x4 a = *(const f32x4*)p;
  f32x4 b = *(const f32x4*)(p + 4);
  a = a * sc; b = b * sc;
  f16x8 r;
  r[0]=(f16)a[0]; r[1]=(f16)a[1]; r[2]=(f16)a[2]; r[3]=(f16)a[3];
  r[4]=(f16)b[0]; r[5]=(f16)b[1]; r[6]=(f16)b[2]; r[7]=(f16)b[3];
  return r;
}
__device__ __forceinline__ f16x8 cvt8(f32x4 a, f32x4 b) {
  f16x8 r;
  r[0]=(f16)a[0]; r[1]=(f16)a[1]; r[2]=(f16)a[2]; r[3]=(f16)a[3];
  r[4]=(f16)b[0]; r[5]=(f16)b[1]; r[6]=(f16)b[2]; r[7]=(f16)b[3];
  return r;
}

// 3-layer MLP core for node/global kernels (4-wave, h [32][136], unswapped; proven).
template<int KSL, int W1RL, int W1O, int W2O, int W3O>
__device__ __forceinline__ void mlp3_core(f16* __restrict__ sm,
    const float* __restrict__ b1l, const float* __restrict__ b2l,
    const float* __restrict__ b3l,
    const f16x8 (&A1)[2][KSL], const int hb, const int r15, const int g,
    f32x4 (&acc3)[2][4])
{
  #pragma unroll
  for (int hh = 0; hh < 2; ++hh) {
    f32x4 acc[2][4];
    #pragma unroll
    for (int nt = 0; nt < 4; ++nt) {
      const float bv = b1l[(hh*4 + nt)*16 + r15];
      acc[0][nt] = (f32x4){bv, bv, bv, bv};
      acc[1][nt] = acc[0][nt];
    }
    #pragma unroll
    for (int s = 0; s < KSL; ++s) {
      #pragma unroll
      for (int nt = 0; nt < 4; ++nt) {
        const f16x8 bf = *(const f16x8*)&sm[W1O + ((hh*4+nt)*16 + r15) * W1RL + s*32 + g*8];
        acc[0][nt] = MFMA16(A1[0][s], bf, acc[0][nt]);
        acc[1][nt] = MFMA16(A1[1][s], bf, acc[1][nt]);
      }
    }
    #pragma unroll
    for (int mt = 0; mt < 2; ++mt)
      #pragma unroll
      for (int nt = 0; nt < 4; ++nt)
        #pragma unroll
        for (int i = 0; i < 4; ++i)
          sm[hb + (mt*16 + g*4 + i)*136 + (hh*4+nt)*16 + r15] =
              (f16)fmaxf(acc[mt][nt][i], 0.f);
  }

  f16x8 A2[2][4];
  #pragma unroll
  for (int mt = 0; mt < 2; ++mt)
    #pragma unroll
    for (int s = 0; s < 4; ++s)
      A2[mt][s] = *(const f16x8*)&sm[hb + (mt*16 + r15)*136 + s*32 + g*8];

  #pragma unroll
  for (int hh = 0; hh < 2; ++hh) {
    f32x4 acc[2][4];
    #pragma unroll
    for (int nt = 0; nt < 4; ++nt) {
      const float bv = b2l[(hh*4 + nt)*16 + r15];
      acc[0][nt] = (f32x4){bv, bv, bv, bv};
      acc[1][nt] = acc[0][nt];
    }
    #pragma unroll
    for (int s = 0; s < 4; ++s) {
      #pragma unroll
      for (int nt = 0; nt < 4; ++nt) {
        const f16x8 bf = *(const f16x8*)&sm[W2O + ((hh*4+nt)*16 + r15)*136 + s*32 + g*8];
        acc[0][nt] = MFMA16(A2[0][s], bf, acc[0][nt]);
        acc[1][nt] = MFMA16(A2[1][s], bf, acc[1][nt]);
      }
    }
    #pragma unroll
    for (int mt = 0; mt < 2; ++mt)
      #pragma unroll
      for (int nt = 0; nt < 4; ++nt)
        #pragma unroll
        for (int i = 0; i < 4; ++i)
          sm[hb + (mt*16 + g*4 + i)*136 + (hh*4+nt)*16 + r15] =
              (f16)fmaxf(acc[mt][nt][i], 0.f);
  }

  f16x8 A3[2][4];
  #pragma unroll
  for (int mt = 0; mt < 2; ++mt)
    #pragma unroll
    for (int s = 0; s < 4; ++s)
      A3[mt][s] = *(const f16x8*)&sm[hb + (mt*16 + r15)*136 + s*32 + g*8];

  #pragma unroll
  for (int nt = 0; nt < 4; ++nt) {
    const float bv = b3l[nt*16 + r15];
    acc3[0][nt] = (f32x4){bv, bv, bv, bv};
    acc3[1][nt] = acc3[0][nt];
  }
  #pragma unroll
  for (int s = 0; s < 4; ++s) {
    #pragma unroll
    for (int nt = 0; nt < 4; ++nt) {
      const f16x8 bf = *(const f16x8*)&sm[W3O + (nt*16 + r15)*136 + s*32 + g*8];
      acc3[0][nt] = MFMA16(A3[0][s], bf, acc3[0][nt]);
      acc3[1][nt] = MFMA16(A3[1][s], bf, acc3[1][nt]);
    }
  }
}

// ---------------- weight prep: all 9 transposes in ONE launch ----------------
__global__ void transpose_all(
    const float* __restrict__ e1, const float* __restrict__ e2, const float* __restrict__ e3,
    const float* __restrict__ n1, const float* __restrict__ n2, const float* __restrict__ n3,
    const float* __restrict__ q1, const float* __restrict__ q2, const float* __restrict__ q3,
    f16* __restrict__ dst) {
  int tid = blockIdx.x * 256 + threadIdx.x;
  const int o1=32768,o2=49152,o3=57344,o4=81920,o5=98304,o6=106496,o7=131072,o8=147456,o9=155648;
  if (tid >= o9) return;
  const float* src; int in, od, rel;
  if      (tid < o1) { src=e1; in=256; od=128; rel=tid;    }
  else if (tid < o2) { src=e2; in=128; od=128; rel=tid-o1; }
  else if (tid < o3) { src=e3; in=128; od=64;  rel=tid-o2; }
  else if (tid < o4) { src=n1; in=192; od=128; rel=tid-o3; }
  else if (tid < o5) { src=n2; in=128; od=128; rel=tid-o4; }
  else if (tid < o6) { src=n3; in=128; od=64;  rel=tid-o5; }
  else if (tid < o7) { src=q1; in=192; od=128; rel=tid-o6; }
  else if (tid < o8) { src=q2; in=128; od=128; rel=tid-o7; }
  else               { src=q3; in=128; od=64;  rel=tid-o8; }
  int o = rel / in, i = rel - o * in;
  dst[tid] = (f16)src[(size_t)i * od + o];
}

// ---------------- f16 copies of x and u ----------------
__global__ void cvt_xu(const float* __restrict__ x, const float* __restrict__ u,
                       f16* __restrict__ xh, f16* __restrict__ uh) {
  const int XT = NN * 64 / 4;
  const int UT = BBATCH * 64 / 4;
  int tid = blockIdx.x * 256 + threadIdx.x;
  for (int i = tid; i < XT; i += gridDim.x * 256) {
    f32x4 v = *(const f32x4*)&x[(size_t)i * 4];
    f16x4 h; h[0]=(f16)v[0]; h[1]=(f16)v[1]; h[2]=(f16)v[2]; h[3]=(f16)v[3];
    *(f16x4*)&xh[(size_t)i * 4] = h;
  }
  if (tid < UT) {
    f32x4 v = *(const f32x4*)&u[(size_t)tid * 4];
    f16x4 h; h[0]=(f16)v[0]; h[1]=(f16)v[1]; h[2]=(f16)v[2]; h[3]=(f16)v[3];
    *(f16x4*)&uh[(size_t)tid * 4] = h;
  }
}

// ---------------- CSR build ----------------
__global__ void count_kernel(const int* __restrict__ ei, int* __restrict__ deg) {
  int tid = blockIdx.x * 256 + threadIdx.x;
  if (tid < EE) atomicAdd(&deg[ei[tid]], 1);
}

__global__ __launch_bounds__(1024) void scan_kernel(const int* __restrict__ deg,
                                                    int* __restrict__ offs,
                                                    int* __restrict__ cursor) {
  const int t = threadIdx.x;
  const int per = (NN + 1023) / 1024;
  const int s0 = t * per;
  int s1 = s0 + per; if (s1 > NN) s1 = NN;
  int sum = 0;
  for (int i = s0; i < s1; ++i) sum += deg[i];
  const int lane = t & 63, wid = t >> 6;
  int v = sum;
  #pragma unroll
  for (int off = 1; off < 64; off <<= 1) {
    int o = __shfl_up(v, off);
    if (lane >= off) v += o;
  }
  __shared__ int wsums[16];
  __shared__ int wexcl[16];
  if (lane == 63) wsums[wid] = v;
  __syncthreads();
  if (t == 0) { int run = 0; for (int k = 0; k < 16; ++k) { wexcl[k] = run; run += wsums[k]; } }
  __syncthreads();
  int run = wexcl[wid] + v - sum;
  for (int i = s0; i < s1; ++i) { int d = deg[i]; offs[i] = run; cursor[i] = run; run += d; }
  if (t == 1023) offs[NN] = run;
}

__global__ void fill_kernel(const int* __restrict__ ei, int* __restrict__ cursor,
                            int* __restrict__ elist) {
  int tid = blockIdx.x * 256 + threadIdx.x;
  if (tid < EE) {
    int r = ei[tid];
    int pos = atomicAdd(&cursor[r], 1);
    elist[pos] = tid;
  }
}

// ---------------- edge MLP: swapped-operand, 1024 thr / 16 waves / 4 waves-per-SIMD ----------------
// __launch_bounds__(1024, 2): empirical hipcc law cap = 256/arg2 -> 128 VGPRs, natural demand
// ~116 -> no spill; 116*4 = 464 <= 512 VGPRs/SIMD keeps all 16 waves resident (4/SIMD).
// (1024,4) and plain (1024) both capped at 64 -> spill (R9/R10 regressions).
__global__ __launch_bounds__(1024, 2) void edge_mlp_kernel(
    const f16* __restrict__ xh, const float* __restrict__ ea,
    const f16* __restrict__ uh, const int* __restrict__ ei,
    const int* __restrict__ batch,
    const f16* __restrict__ w1t, const f16* __restrict__ w2t, const f16* __restrict__ w3t,
    const float* __restrict__ b1, const float* __restrict__ b2, const float* __restrict__ b3,
    float* __restrict__ e_out)
{
  __shared__ __align__(16) f16 sm[ELDS];
  const int t = threadIdx.x;
  for (int c = t; c < 4096; c += 1024) { int r = c >> 5, kc = c & 31;
    *(uint4*)&sm[EW1_OFF + r*EW1_RL + kc*8] = *(const uint4*)&w1t[r*256 + kc*8]; }
  for (int c = t; c < 2048; c += 1024) { int r = c >> 4, kc = c & 15;
    *(uint4*)&sm[EW2_OFF + r*136 + kc*8] = *(const uint4*)&w2t[r*128 + kc*8]; }
  if (t < 1024) { int c = t; int r = c >> 4, kc = c & 15;
    *(uint4*)&sm[EW3_OFF + r*136 + kc*8] = *(const uint4*)&w3t[r*128 + kc*8]; }
  float* bias = (float*)&sm[EB_OFF];
  if (t < 128) { bias[t] = b1[t]; bias[128 + t] = b2[t]; }
  else if (t < 192) { bias[256 + (t - 128)] = b3[t - 128]; }
  __syncthreads();

  const int l = t & 63, w = t >> 6;         // w in 0..15
  const int r15 = l & 15, g = l >> 4;       // r15 = m-lane, g = n-subrow group
  const int hb = EH_OFF + w * (16 * 72);
  const int NT = EE / 512;                  // 3125
  const int stride = gridDim.x;
  const int t0 = blockIdx.x;

  int rC[2], cC[2], bC[2];   // indices for tile T+1
  int rN[2], cN[2], bN[2];   // indices for tile T+2 (arriving)
  f16x8 Bx[2][6];            // next-tile x/u frags in flight (f16, direct frag layout)
  f32x4 Gea[2][2][2];        // next-tile edge_attr in flight (f32)

  auto issueXU = [&](const int (&rr)[2], const int (&cc)[2], const int (&bb)[2]) {
    #pragma unroll
    for (int mt = 0; mt < 2; ++mt) {
      const f16* pr = xh + (size_t)rr[mt] * 64 + g * 8;
      const f16* pc = xh + (size_t)cc[mt] * 64 + g * 8;
      const f16* pu = uh + (size_t)bb[mt] * 64 + g * 8;
      Bx[mt][0] = *(const f16x8*)pr;        Bx[mt][1] = *(const f16x8*)(pr + 32);
      Bx[mt][2] = *(const f16x8*)pc;        Bx[mt][3] = *(const f16x8*)(pc + 32);
      Bx[mt][4] = *(const f16x8*)pu;        Bx[mt][5] = *(const f16x8*)(pu + 32);
    }
  };
  auto issueEA = [&](int tt) {
    #pragma unroll
    for (int mt = 0; mt < 2; ++mt) {
      const float* pe = ea + ((size_t)(tt * 512 + w * 32 + mt * 16 + r15)) * 64 + g * 8;
      #pragma unroll
      for (int ss = 0; ss < 2; ++ss) {
        Gea[mt][ss][0] = *(const f32x4*)(pe + ss * 32);
        Gea[mt][ss][1] = *(const f32x4*)(pe + ss * 32 + 4);
      }
    }
  };

  // prologue
  {
    int rr[2], cc[2], bb[2];
    #pragma unroll
    for (int mt = 0; mt < 2; ++mt) {
      const int eid = t0 * 512 + w * 32 + mt * 16 + r15;
      rr[mt] = ei[eid]; cc[mt] = ei[EE + eid];
    }
    #pragma unroll
    for (int mt = 0; mt < 2; ++mt) bb[mt] = batch[rr[mt]];
    issueXU(rr, cc, bb); issueEA(t0);
    int t1 = t0 + stride; if (t1 >= NT) t1 = t0;
    #pragma unroll
    for (int mt = 0; mt < 2; ++mt) {
      const int eid = t1 * 512 + w * 32 + mt * 16 + r15;
      rC[mt] = ei[eid]; cC[mt] = ei[EE + eid];
    }
    #pragma unroll
    for (int mt = 0; mt < 2; ++mt) bC[mt] = batch[rC[mt]];
  }

  for (int tile = t0; tile < NT; tile += stride) {
    // ---- assemble data frags (B-operand) for THIS tile ----
    f16x8 A[2][8];
    #pragma unroll
    for (int mt = 0; mt < 2; ++mt) {
      A[mt][0] = Bx[mt][0]; A[mt][1] = Bx[mt][1];
      A[mt][2] = Bx[mt][2]; A[mt][3] = Bx[mt][3];
      A[mt][4] = cvt8(Gea[mt][0][0], Gea[mt][0][1]);
      A[mt][5] = cvt8(Gea[mt][1][0], Gea[mt][1][1]);
      A[mt][6] = Bx[mt][4]; A[mt][7] = Bx[mt][5];
    }

    // prefetch ei for T+2 (cheap, long cover)
    int t2 = tile + 2 * stride; if (t2 >= NT) t2 = t0;
    #pragma unroll
    for (int mt = 0; mt < 2; ++mt) {
      const int eid = t2 * 512 + w * 32 + mt * 16 + r15;
      rN[mt] = ei[eid]; cN[mt] = ei[EE + eid];
    }

    // ---- layer 1 (swapped): D1[n1][m], n1=128 (8 a-tiles), K=256 ----
    f32x4 acc1[2][8];
    #pragma unroll
    for (int a = 0; a < 8; ++a) {
      const f32x4 bv = *(const f32x4*)&bias[a*16 + g*4];
      acc1[0][a] = bv; acc1[1][a] = bv;
    }
    #pragma unroll
    for (int s = 0; s < 8; ++s)
      #pragma unroll
      for (int a = 0; a < 8; ++a) {
        const f16x8 wf = *(const f16x8*)&sm[EW1_OFF + (a*16 + r15)*EW1_RL + s*32 + g*8];
        acc1[0][a] = MFMA16(wf, A[0][s], acc1[0][a]);
        acc1[1][a] = MFMA16(wf, A[1][s], acc1[1][a]);
      }

    // batch for T+2 (rN arrived during layer 1)
    #pragma unroll
    for (int mt = 0; mt < 2; ++mt) bN[mt] = batch[rN[mt]];

    // ---- dance 1: packed b64 writes, per (mt, hh) pass -> B2 frags ----
    f16x8 B2[2][4];
    #pragma unroll
    for (int mt = 0; mt < 2; ++mt)
      #pragma unroll
      for (int hh = 0; hh < 2; ++hh) {
        #pragma unroll
        for (int ap = 0; ap < 4; ++ap) {
          const f32x4 v = acc1[mt][hh*4 + ap];
          f16x4 hv;
          hv[0]=(f16)fmaxf(v[0],0.f); hv[1]=(f16)fmaxf(v[1],0.f);
          hv[2]=(f16)fmaxf(v[2],0.f); hv[3]=(f16)fmaxf(v[3],0.f);
          *(f16x4*)&sm[hb + r15*72 + ap*16 + g*4] = hv;
        }
        #pragma unroll
        for (int sl = 0; sl < 2; ++sl)
          B2[mt][hh*2 + sl] = *(const f16x8*)&sm[hb + r15*72 + sl*32 + g*8];
      }

    // issue next tile's x/u loads (covered by layers 2-3)
    int t1 = tile + stride; if (t1 >= NT) t1 = t0;
    issueXU(rC, cC, bC);

    // ---- layer 2 (swapped): n2=128, K=128 ----
    f32x4 acc2[2][8];
    #pragma unroll
    for (int a = 0; a < 8; ++a) {
      const f32x4 bv = *(const f32x4*)&bias[128 + a*16 + g*4];
      acc2[0][a] = bv; acc2[1][a] = bv;
    }
    #pragma unroll
    for (int s = 0; s < 4; ++s)
      #pragma unroll
      for (int a = 0; a < 8; ++a) {
        const f16x8 wf = *(const f16x8*)&sm[EW2_OFF + (a*16 + r15)*136 + s*32 + g*8];
        acc2[0][a] = MFMA16(wf, B2[0][s], acc2[0][a]);
        acc2[1][a] = MFMA16(wf, B2[1][s], acc2[1][a]);
      }

    // ---- dance 2 -> B3 frags ----
    f16x8 B3[2][4];
    #pragma unroll
    for (int mt = 0; mt < 2; ++mt)
      #pragma unroll
      for (int hh = 0; hh < 2; ++hh) {
        #pragma unroll
        for (int ap = 0; ap < 4; ++ap) {
          const f32x4 v = acc2[mt][hh*4 + ap];
          f16x4 hv;
          hv[0]=(f16)fmaxf(v[0],0.f); hv[1]=(f16)fmaxf(v[1],0.f);
          hv[2]=(f16)fmaxf(v[2],0.f); hv[3]=(f16)fmaxf(v[3],0.f);
          *(f16x4*)&sm[hb + r15*72 + ap*16 + g*4] = hv;
        }
        #pragma unroll
        for (int sl = 0; sl < 2; ++sl)
          B3[mt][hh*2 + sl] = *(const f16x8*)&sm[hb + r15*72 + sl*32 + g*8];
      }

    // issue next tile's ea loads (covered by layer 3 + store)
    issueEA(t1);

    // ---- layer 3 (swapped): n3=64, K=128 ----
    f32x4 acc3[2][4];
    #pragma unroll
    for (int a = 0; a < 4; ++a) {
      const f32x4 bv = *(const f32x4*)&bias[256 + a*16 + g*4];
      acc3[0][a] = bv; acc3[1][a] = bv;
    }
    #pragma unroll
    for (int s = 0; s < 4; ++s)
      #pragma unroll
      for (int a = 0; a < 4; ++a) {
        const f16x8 wf = *(const f16x8*)&sm[EW3_OFF + (a*16 + r15)*136 + s*32 + g*8];
        acc3[0][a] = MFMA16(wf, B3[0][s], acc3[0][a]);
        acc3[1][a] = MFMA16(wf, B3[1][s], acc3[1][a]);
      }

    // ---- epilogue: vector stores (lane holds e[m][16a+4g .. +3]) ----
    const int base = tile * 512 + w * 32;
    #pragma unroll
    for (int mt = 0; mt < 2; ++mt) {
      const int m = base + mt * 16 + r15;
      #pragma unroll
      for (int a = 0; a < 4; ++a)
        *(f32x4*)&e_out[(size_t)m * 64 + a*16 + g*4] = acc3[mt][a];
    }

    #pragma unroll
    for (int mt = 0; mt < 2; ++mt) { rC[mt] = rN[mt]; cC[mt] = cN[mt]; bC[mt] = bN[mt]; }
  }
}

// ---------------- n_agg sums via CSR gather (8-deep ILP) ----------------
__global__ void nsum_kernel(const float* __restrict__ e_src, const int* __restrict__ offs,
                            const int* __restrict__ elist, float* __restrict__ n_sum) {
  const int l = threadIdx.x & 63;
  const int wid = (blockIdx.x * blockDim.x + threadIdx.x) >> 6;
  const int nw = (gridDim.x * blockDim.x) >> 6;
  for (int node = wid; node < NN; node += nw) {
    const int s = offs[node], e = offs[node + 1];
    float acc = 0.f;
    int j = s;
    for (; j + 8 <= e; j += 8) {
      float v0 = e_src[(size_t)elist[j]   * 64 + l];
      float v1 = e_src[(size_t)elist[j+1] * 64 + l];
      float v2 = e_src[(size_t)elist[j+2] * 64 + l];
      float v3 = e_src[(size_t)elist[j+3] * 64 + l];
      float v4 = e_src[(size_t)elist[j+4] * 64 + l];
      float v5 = e_src[(size_t)elist[j+5] * 64 + l];
      float v6 = e_src[(size_t)elist[j+6] * 64 + l];
      float v7 = e_src[(size_t)elist[j+7] * 64 + l];
      acc += ((v0 + v1) + (v2 + v3)) + ((v4 + v5) + (v6 + v7));
    }
    for (; j < e; ++j) acc += e_src[(size_t)elist[j] * 64 + l];
    n_sum[(size_t)node * 64 + l] = acc;
  }
}

// ---------------- node MLP (persistent: stage weights once, loop tiles) ----------------
__global__ __launch_bounds__(256, 1) void node_mlp_kernel(
    const float* __restrict__ x, const float* __restrict__ u,
    const int* __restrict__ batch, const float* __restrict__ n_sum,
    const int* __restrict__ deg,
    const f16* __restrict__ w1t, const f16* __restrict__ w2t, const f16* __restrict__ w3t,
    const float* __restrict__ b1, const float* __restrict__ b2, const float* __restrict__ b3,
    float* __restrict__ xn_out)
{
  __shared__ __align__(16) f16 sm[NLDS];
  const int t = threadIdx.x;
  for (int c = t; c < 3072; c += 256) { int r = c / 24, kc = c - r * 24;
    *(uint4*)&sm[NW1_OFF + r*NW1_RL + kc*8] = *(const uint4*)&w1t[r*192 + kc*8]; }
  for (int c = t; c < 2048; c += 256) { int r = c >> 4, kc = c & 15;
    *(uint4*)&sm[NW2_OFF + r*136 + kc*8] = *(const uint4*)&w2t[r*128 + kc*8]; }
  for (int c = t; c < 1024; c += 256) { int r = c >> 4, kc = c & 15;
    *(uint4*)&sm[NW3_OFF + r*136 + kc*8] = *(const uint4*)&w3t[r*128 + kc*8]; }
  float* bias = (float*)&sm[NB_OFF];
  if (t < 128) { bias[t] = b1[t]; bias[128 + t] = b2[t]; }
  if (t < 64)  { bias[256 + t] = b3[t]; }
  __syncthreads();

  const int l = t & 63, w = t >> 6;
  const int r15 = l & 15, g = l >> 4;
  const int hb = NH_OFF + w * (32 * 136);
  const int NTT = (NN + 127) / 128;   // 391

  for (int tile = blockIdx.x; tile < NTT; tile += gridDim.x) {
    const int base = tile * 128 + w * 32;
    f16x8 A1[2][6];
    #pragma unroll
    for (int mt = 0; mt < 2; ++mt) {
      int raw = base + mt * 16 + r15;
      int node = raw < NN ? raw : NN - 1;
      float inv = 1.0f / fmaxf((float)deg[node], 1.0f);
      const float* sA = n_sum + (size_t)node * 64;
      const float* sB = x + (size_t)node * 64;
      const float* sC = u + (size_t)batch[node] * 64;
      #pragma unroll
      for (int s = 0; s < 6; ++s) {
        const int off = (s & 1) * 32 + g * 8;
        if (s < 2)      A1[mt][s] = pack8s(sA + off, inv);
        else if (s < 4) A1[mt][s] = pack8(sB + off);
        else            A1[mt][s] = pack8(sC + off);
      }
    }
    f32x4 acc3[2][4];
    mlp3_core<6, NW1_RL, NW1_OFF, NW2_OFF, NW3_OFF>(sm, bias, bias + 128, bias + 256,
                                                    A1, hb, r15, g, acc3);
    #pragma unroll
    for (int mt = 0; mt < 2; ++mt)
      #pragma unroll
      for (int nt = 0; nt < 4; ++nt)
        #pragma unroll
        for (int i = 0; i < 4; ++i) {
          const int m = base + mt * 16 + g * 4 + i;
          if (m < NN) xn_out[(size_t)m * 64 + nt * 16 + r15] = acc3[mt][nt][i];
        }
  }
}

// ---------------- batch segment starts ----------------
__global__ void bstart_kernel(const int* __restrict__ batch, int* __restrict__ bstart) {
  int tid = blockIdx.x * 256 + threadIdx.x;
  if (tid >= NN) return;
  int b = batch[tid];
  if (tid == 0) { for (int k = 0; k <= b; ++k) bstart[k] = 0; }
  else { int pb = batch[tid - 1]; for (int k = pb + 1; k <= b; ++k) bstart[k] = tid; }
  if (tid == NN - 1) { for (int k = b + 1; k <= BBATCH; ++k) bstart[k] = NN; }
}

// ---------------- per-batch segmented sums ----------------
__global__ void batch_sum_kernel(const float* __restrict__ xn, const float* __restrict__ n_sum,
                                 const int* __restrict__ deg, const int* __restrict__ bstart,
                                 float* __restrict__ nbsum, float* __restrict__ ebsum,
                                 int* __restrict__ ncnt, int* __restrict__ ecnt) {
  __shared__ float red0[256];
  __shared__ float red1[256];
  __shared__ int   redi[256];
  const int b = blockIdx.x;
  const int s = bstart[b], e = bstart[b + 1];
  const int t = threadIdx.x, c = t & 63, j0 = t >> 6;
  float xs = 0.f, ns = 0.f; int dc = 0;
  for (int j = s + j0; j < e; j += 4) {
    xs += xn[(size_t)j * 64 + c];
    ns += n_sum[(size_t)j * 64 + c];
    if (c == 0) dc += deg[j];
  }
  red0[t] = xs; red1[t] = ns; redi[t] = dc;
  __syncthreads();
  if (t < 128) { red0[t] += red0[t + 128]; red1[t] += red1[t + 128]; redi[t] += redi[t + 128]; }
  __syncthreads();
  if (t < 64) {
    float a0 = red0[t] + red0[t + 64];
    float a1 = red1[t] + red1[t + 64];
    nbsum[b * 64 + t] = a0;
    ebsum[b * 64 + t] = a1;
    if (t == 0) { ncnt[b] = e - s; ecnt[b] = redi[0] + redi[64]; }
  }
}

// ---------------- global MLP ----------------
__global__ __launch_bounds__(256, 1) void global_mlp_kernel(
    const float* __restrict__ u, const float* __restrict__ nbsum,
    const float* __restrict__ ebsum, const int* __restrict__ ncnt,
    const int* __restrict__ ecnt,
    const f16* __restrict__ w1t, const f16* __restrict__ w2t, const f16* __restrict__ w3t,
    const float* __restrict__ b1, const float* __restrict__ b2, const float* __restrict__ b3,
    float* __restrict__ un_out)
{
  __shared__ __align__(16) f16 sm[NLDS];
  const int t = threadIdx.x;
  for (int c = t; c < 3072; c += 256) { int r = c / 24, kc = c - r * 24;
    *(uint4*)&sm[NW1_OFF + r*NW1_RL + kc*8] = *(const uint4*)&w1t[r*192 + kc*8]; }
  for (int c = t; c < 2048; c += 256) { int r = c >> 4, kc = c & 15;
    *(uint4*)&sm[NW2_OFF + r*136 + kc*8] = *(const uint4*)&w2t[r*128 + kc*8]; }
  for (int c = t; c < 1024; c += 256) { int r = c >> 4, kc = c & 15;
    *(uint4*)&sm[NW3_OFF + r*136 + kc*8] = *(const uint4*)&w3t[r*128 + kc*8]; }
  float* bias = (float*)&sm[NB_OFF];
  if (t < 128) { bias[t] = b1[t]; bias[128 + t] = b2[t]; }
  if (t < 64)  { bias[256 + t] = b3[t]; }
  __syncthreads();

  const int l = t & 63, w = t >> 6;
  const int r15 = l & 15, g = l >> 4;
  const int hb = NH_OFF + w * (32 * 136);
  const int base = blockIdx.x * 128 + w * 32;

  f16x8 A1[2][6];
  #pragma unroll
  for (int mt = 0; mt < 2; ++mt) {
    const int r = base + mt * 16 + r15;
    const float invn = 1.0f / fmaxf((float)ncnt[r], 1.0f);
    const float inve = 1.0f / fmaxf((float)ecnt[r], 1.0f);
    const float* sA = u + (size_t)r * 64;
    const float* sB = nbsum + (size_t)r * 64;
    const float* sC = ebsum + (size_t)r * 64;
    #pragma unroll
    for (int s = 0; s < 6; ++s) {
      const int off = (s & 1) * 32 + g * 8;
      if (s < 2)      A1[mt][s] = pack8(sA + off);
      else if (s < 4) A1[mt][s] = pack8s(sB + off, invn);
      else            A1[mt][s] = pack8s(sC + off, inve);
    }
  }
  f32x4 acc3[2][4];
  mlp3_core<6, NW1_RL, NW1_OFF, NW2_OFF, NW3_OFF>(sm, bias, bias + 128, bias + 256,
                                                  A1, hb, r15, g, acc3);
  #pragma unroll
  for (int mt = 0; mt < 2; ++mt)
    #pragma unroll
    for (int nt = 0; nt < 4; ++nt)
      #pragma unroll
      for (int i = 0; i < 4; ++i) {
        const int m = base + mt * 16 + g * 4 + i;
        un_out[(size_t)m * 64 + nt * 16 + r15] = acc3[mt][nt][i];
      }
}

// ---------------- host launcher ----------------
extern "C" void kernel_launch(void* const* d_in, const int* in_sizes, int n_in,
                              void* d_out, int out_size, void* d_ws, size_t ws_size,
                              hipStream_t stream)
{
  (void)in_sizes; (void)n_in; (void)out_size; (void)ws_size;
  const float* x     = (const float*)d_in[0];
  const float* ea    = (const float*)d_in[1];
  const float* u     = (const float*)d_in[2];
  const int*   ei    = (const int*)d_in[3];
  const int*   batch = (const int*)d_in[4];
  const float* ew1 = (const float*)d_in[5];  const float* eb1 = (const float*)d_in[6];
  const float* ew2 = (const float*)d_in[7];  const float* eb2 = (const float*)d_in[8];
  const float* ew3 = (const float*)d_in[9];  const float* eb3 = (const float*)d_in[10];
  const float* nw1 = (const float*)d_in[11]; const float* nb1 = (const float*)d_in[12];
  const float* nw2 = (const float*)d_in[13]; const float* nb2 = (const float*)d_in[14];
  const float* nw3 = (const float*)d_in[15]; const float* nb3 = (const float*)d_in[16];
  const float* gw1 = (const float*)d_in[17]; const float* gb1 = (const float*)d_in[18];
  const float* gw2 = (const float*)d_in[19]; const float* gb2 = (const float*)d_in[20];
  const float* gw3 = (const float*)d_in[21]; const float* gb3 = (const float*)d_in[22];

  float* xn_out = (float*)d_out;
  float* e_out  = xn_out + (size_t)NN * DD;
  float* un_out = e_out + (size_t)EE * DD;

  char* p = (char*)d_ws;
  auto alloc = [&](size_t bytes) -> void* {
    void* r = (void*)p; p += (bytes + 255) & ~(size_t)255; return r;
  };
  // NOTE: 9 weight buffers must stay contiguous in this order (transpose_all writes linearly)
  f16* wtE1 = (f16*)alloc(256 * 128 * 2);
  f16* wtE2 = (f16*)alloc(128 * 128 * 2);
  f16* wtE3 = (f16*)alloc(128 * 64 * 2);
  f16* wtN1 = (f16*)alloc(192 * 128 * 2);
  f16* wtN2 = (f16*)alloc(128 * 128 * 2);
  f16* wtN3 = (f16*)alloc(128 * 64 * 2);
  f16* wtG1 = (f16*)alloc(192 * 128 * 2);
  f16* wtG2 = (f16*)alloc(128 * 128 * 2);
  f16* wtG3 = (f16*)alloc(128 * 64 * 2);
  int* deg    = (int*)alloc((size_t)NN * 4);
  int* offs   = (int*)alloc((size_t)(NN + 1) * 4);
  int* cursor = (int*)alloc((size_t)NN * 4);
  int* elist  = (int*)alloc((size_t)EE * 4);
  int* bstart = (int*)alloc((size_t)(BBATCH + 1) * 4);
  float* nbsum = (float*)alloc((size_t)BBATCH * 64 * 4);
  float* ebsum = (float*)alloc((size_t)BBATCH * 64 * 4);
  int* ncnt = (int*)alloc((size_t)BBATCH * 4);
  int* ecnt = (int*)alloc((size_t)BBATCH * 4);
  float* n_sum = (float*)alloc((size_t)NN * 64 * 4);
  f16* xh = (f16*)alloc((size_t)NN * 64 * 2);
  f16* uh = (f16*)alloc((size_t)BBATCH * 64 * 2);

  transpose_all<<<dim3(608), dim3(256), 0, stream>>>(
      ew1, ew2, ew3, nw1, nw2, nw3, gw1, gw2, gw3, wtE1);
  cvt_xu<<<dim3(1024), dim3(256), 0, stream>>>(x, u, xh, uh);

  hipMemsetAsync(deg, 0, (size_t)NN * 4, stream);
  count_kernel<<<dim3(6250), dim3(256), 0, stream>>>(ei, deg);
  scan_kernel<<<dim3(1), dim3(1024), 0, stream>>>(deg, offs, cursor);
  fill_kernel<<<dim3(6250), dim3(256), 0, stream>>>(ei, cursor, elist);

  edge_mlp_kernel<<<dim3(256), dim3(1024), 0, stream>>>(
      xh, ea, uh, ei, batch, wtE1, wtE2, wtE3, eb1, eb2, eb3, e_out);

  nsum_kernel<<<dim3(4096), dim3(256), 0, stream>>>(e_out, offs, elist, n_sum);

  node_mlp_kernel<<<dim3(256), dim3(256), 0, stream>>>(
      x, u, batch, n_sum, deg, wtN1, wtN2, wtN3, nb1, nb2, nb3, xn_out);

  bstart_kernel<<<dim3((NN + 255) / 256), dim3(256), 0, stream>>>(batch, bstart);
  batch_sum_kernel<<<dim3(BBATCH), dim3(256), 0, stream>>>(
      xn_out, n_sum, deg, bstart, nbsum, ebsum, ncnt, ecnt);

  global_mlp_kernel<<<dim3(2), dim3(256), 0, stream>>>(
      u, nbsum, ebsum, ncnt, ecnt, wtG1, wtG2, wtG3, gb1, gb2, gb3, un_out);
}

// Round 12
// 731.282 us; speedup vs baseline: 1.5079x; 1.4886x over previous
//
#include <hip/hip_runtime.h>

#define NN 50000
#define EE 1600000
#define BBATCH 256
#define DD 64

typedef _Float16 f16;
typedef _Float16 f16x4 __attribute__((ext_vector_type(4)));
typedef _Float16 f16x8 __attribute__((ext_vector_type(8)));
typedef float f32x4 __attribute__((ext_vector_type(4)));

#define MFMA16(a,b,c) __builtin_amdgcn_mfma_f32_16x16x32_f16((a),(b),(c),0,0,0)

// ---------------- LDS layouts (in halves) ----------------
// Edge kernel (512 thr / 8 waves, R8-proven): W1 [128][256->264], W2 [128][136], W3 [64][136],
// h 8x[16][72], bias 320 f32. Total 139520 B.
constexpr int EW1_RL  = 264;
constexpr int EW1_OFF = 0;
constexpr int EW2_OFF = EW1_OFF + 128 * EW1_RL;   // 33792
constexpr int EW3_OFF = EW2_OFF + 128 * 136;      // 51200
constexpr int EH_OFF  = EW3_OFF + 64 * 136;       // 59904
constexpr int EB_OFF  = EH_OFF + 8 * 16 * 72;     // 69120
constexpr int ELDS    = EB_OFF + 640;             // 69760 halves = 139520 B

// Node/global kernel (256 thr / 4 waves).
constexpr int NW1_RL  = 200;
constexpr int NW1_OFF = 0;
constexpr int NW2_OFF = NW1_OFF + 128 * NW1_RL;   // 25600
constexpr int NW3_OFF = NW2_OFF + 128 * 136;      // 43008
constexpr int NH_OFF  = NW3_OFF + 64 * 136;       // 51712
constexpr int NB_OFF  = NH_OFF + 4 * 32 * 136;    // 69120
constexpr int NLDS    = NB_OFF + 640;             // 69760 halves = 139520 B

// ---------------- helpers ----------------
__device__ __forceinline__ f16x8 pack8(const float* __restrict__ p) {
  f32x4 a = *(const f32x4*)p;
  f32x4 b = *(const f32x4*)(p + 4);
  f16x8 r;
  r[0]=(f16)a[0]; r[1]=(f16)a[1]; r[2]=(f16)a[2]; r[3]=(f16)a[3];
  r[4]=(f16)b[0]; r[5]=(f16)b[1]; r[6]=(f16)b[2]; r[7]=(f16)b[3];
  return r;
}
__device__ __forceinline__ f16x8 pack8s(const float* __restrict__ p, float sc) {
  f32x4 a = *(const f32x4*)p;
  f32x4 b = *(const f32x4*)(p + 4);
  a = a * sc; b = b * sc;
  f16x8 r;
  r[0]=(f16)a[0]; r[1]=(f16)a[1]; r[2]=(f16)a[2]; r[3]=(f16)a[3];
  r[4]=(f16)b[0]; r[5]=(f16)b[1]; r[6]=(f16)b[2]; r[7]=(f16)b[3];
  return r;
}
__device__ __forceinline__ f16x8 cvt8(f32x4 a, f32x4 b) {
  f16x8 r;
  r[0]=(f16)a[0]; r[1]=(f16)a[1]; r[2]=(f16)a[2]; r[3]=(f16)a[3];
  r[4]=(f16)b[0]; r[5]=(f16)b[1]; r[6]=(f16)b[2]; r[7]=(f16)b[3];
  return r;
}

// 3-layer MLP core for node/global kernels (4-wave, h [32][136], unswapped; proven).
template<int KSL, int W1RL, int W1O, int W2O, int W3O>
__device__ __forceinline__ void mlp3_core(f16* __restrict__ sm,
    const float* __restrict__ b1l, const float* __restrict__ b2l,
    const float* __restrict__ b3l,
    const f16x8 (&A1)[2][KSL], const int hb, const int r15, const int g,
    f32x4 (&acc3)[2][4])
{
  #pragma unroll
  for (int hh = 0; hh < 2; ++hh) {
    f32x4 acc[2][4];
    #pragma unroll
    for (int nt = 0; nt < 4; ++nt) {
      const float bv = b1l[(hh*4 + nt)*16 + r15];
      acc[0][nt] = (f32x4){bv, bv, bv, bv};
      acc[1][nt] = acc[0][nt];
    }
    #pragma unroll
    for (int s = 0; s < KSL; ++s) {
      #pragma unroll
      for (int nt = 0; nt < 4; ++nt) {
        const f16x8 bf = *(const f16x8*)&sm[W1O + ((hh*4+nt)*16 + r15) * W1RL + s*32 + g*8];
        acc[0][nt] = MFMA16(A1[0][s], bf, acc[0][nt]);
        acc[1][nt] = MFMA16(A1[1][s], bf, acc[1][nt]);
      }
    }
    #pragma unroll
    for (int mt = 0; mt < 2; ++mt)
      #pragma unroll
      for (int nt = 0; nt < 4; ++nt)
        #pragma unroll
        for (int i = 0; i < 4; ++i)
          sm[hb + (mt*16 + g*4 + i)*136 + (hh*4+nt)*16 + r15] =
              (f16)fmaxf(acc[mt][nt][i], 0.f);
  }

  f16x8 A2[2][4];
  #pragma unroll
  for (int mt = 0; mt < 2; ++mt)
    #pragma unroll
    for (int s = 0; s < 4; ++s)
      A2[mt][s] = *(const f16x8*)&sm[hb + (mt*16 + r15)*136 + s*32 + g*8];

  #pragma unroll
  for (int hh = 0; hh < 2; ++hh) {
    f32x4 acc[2][4];
    #pragma unroll
    for (int nt = 0; nt < 4; ++nt) {
      const float bv = b2l[(hh*4 + nt)*16 + r15];
      acc[0][nt] = (f32x4){bv, bv, bv, bv};
      acc[1][nt] = acc[0][nt];
    }
    #pragma unroll
    for (int s = 0; s < 4; ++s) {
      #pragma unroll
      for (int nt = 0; nt < 4; ++nt) {
        const f16x8 bf = *(const f16x8*)&sm[W2O + ((hh*4+nt)*16 + r15)*136 + s*32 + g*8];
        acc[0][nt] = MFMA16(A2[0][s], bf, acc[0][nt]);
        acc[1][nt] = MFMA16(A2[1][s], bf, acc[1][nt]);
      }
    }
    #pragma unroll
    for (int mt = 0; mt < 2; ++mt)
      #pragma unroll
      for (int nt = 0; nt < 4; ++nt)
        #pragma unroll
        for (int i = 0; i < 4; ++i)
          sm[hb + (mt*16 + g*4 + i)*136 + (hh*4+nt)*16 + r15] =
              (f16)fmaxf(acc[mt][nt][i], 0.f);
  }

  f16x8 A3[2][4];
  #pragma unroll
  for (int mt = 0; mt < 2; ++mt)
    #pragma unroll
    for (int s = 0; s < 4; ++s)
      A3[mt][s] = *(const f16x8*)&sm[hb + (mt*16 + r15)*136 + s*32 + g*8];

  #pragma unroll
  for (int nt = 0; nt < 4; ++nt) {
    const float bv = b3l[nt*16 + r15];
    acc3[0][nt] = (f32x4){bv, bv, bv, bv};
    acc3[1][nt] = acc3[0][nt];
  }
  #pragma unroll
  for (int s = 0; s < 4; ++s) {
    #pragma unroll
    for (int nt = 0; nt < 4; ++nt) {
      const f16x8 bf = *(const f16x8*)&sm[W3O + (nt*16 + r15)*136 + s*32 + g*8];
      acc3[0][nt] = MFMA16(A3[0][s], bf, acc3[0][nt]);
      acc3[1][nt] = MFMA16(A3[1][s], bf, acc3[1][nt]);
    }
  }
}

// ---------------- fused prep: 9 transposes + x/u f16 cvt + deg count + bstart ----------------
// grid 6250 x 256 = 1.6M threads covers all four jobs in one launch.
__global__ void prep_kernel(
    const float* __restrict__ e1, const float* __restrict__ e2, const float* __restrict__ e3,
    const float* __restrict__ n1, const float* __restrict__ n2, const float* __restrict__ n3,
    const float* __restrict__ q1, const float* __restrict__ q2, const float* __restrict__ q3,
    f16* __restrict__ wdst,
    const float* __restrict__ x, const float* __restrict__ u,
    f16* __restrict__ xh, f16* __restrict__ uh,
    const int* __restrict__ ei, int* __restrict__ deg,
    const int* __restrict__ batch, int* __restrict__ bstart)
{
  const int tid = blockIdx.x * 256 + threadIdx.x;

  // job 1: weight transposes (155648 elems)
  {
    const int o1=32768,o2=49152,o3=57344,o4=81920,o5=98304,o6=106496,o7=131072,o8=147456,o9=155648;
    if (tid < o9) {
      const float* src; int in, od, rel;
      if      (tid < o1) { src=e1; in=256; od=128; rel=tid;    }
      else if (tid < o2) { src=e2; in=128; od=128; rel=tid-o1; }
      else if (tid < o3) { src=e3; in=128; od=64;  rel=tid-o2; }
      else if (tid < o4) { src=n1; in=192; od=128; rel=tid-o3; }
      else if (tid < o5) { src=n2; in=128; od=128; rel=tid-o4; }
      else if (tid < o6) { src=n3; in=128; od=64;  rel=tid-o5; }
      else if (tid < o7) { src=q1; in=192; od=128; rel=tid-o6; }
      else if (tid < o8) { src=q2; in=128; od=128; rel=tid-o7; }
      else               { src=q3; in=128; od=64;  rel=tid-o8; }
      int o = rel / in, i = rel - o * in;
      wdst[tid] = (f16)src[(size_t)i * od + o];
    }
  }

  // job 2: x -> xh (800000 f32x4 groups), u -> uh (4096 groups)
  if (tid < NN * 64 / 4) {
    f32x4 v = *(const f32x4*)&x[(size_t)tid * 4];
    f16x4 h; h[0]=(f16)v[0]; h[1]=(f16)v[1]; h[2]=(f16)v[2]; h[3]=(f16)v[3];
    *(f16x4*)&xh[(size_t)tid * 4] = h;
  }
  if (tid < BBATCH * 64 / 4) {
    f32x4 v = *(const f32x4*)&u[(size_t)tid * 4];
    f16x4 h; h[0]=(f16)v[0]; h[1]=(f16)v[1]; h[2]=(f16)v[2]; h[3]=(f16)v[3];
    *(f16x4*)&uh[(size_t)tid * 4] = h;
  }

  // job 3: degree count
  if (tid < EE) atomicAdd(&deg[ei[tid]], 1);

  // job 4: batch segment starts (batch sorted)
  if (tid < NN) {
    int b = batch[tid];
    if (tid == 0) { for (int k = 0; k <= b; ++k) bstart[k] = 0; }
    else { int pb = batch[tid - 1]; for (int k = pb + 1; k <= b; ++k) bstart[k] = tid; }
    if (tid == NN - 1) { for (int k = b + 1; k <= BBATCH; ++k) bstart[k] = NN; }
  }
}

__global__ __launch_bounds__(1024) void scan_kernel(const int* __restrict__ deg,
                                                    int* __restrict__ offs,
                                                    int* __restrict__ cursor) {
  const int t = threadIdx.x;
  const int per = (NN + 1023) / 1024;
  const int s0 = t * per;
  int s1 = s0 + per; if (s1 > NN) s1 = NN;
  int sum = 0;
  for (int i = s0; i < s1; ++i) sum += deg[i];
  const int lane = t & 63, wid = t >> 6;
  int v = sum;
  #pragma unroll
  for (int off = 1; off < 64; off <<= 1) {
    int o = __shfl_up(v, off);
    if (lane >= off) v += o;
  }
  __shared__ int wsums[16];
  __shared__ int wexcl[16];
  if (lane == 63) wsums[wid] = v;
  __syncthreads();
  if (t == 0) { int run = 0; for (int k = 0; k < 16; ++k) { wexcl[k] = run; run += wsums[k]; } }
  __syncthreads();
  int run = wexcl[wid] + v - sum;
  for (int i = s0; i < s1; ++i) { int d = deg[i]; offs[i] = run; cursor[i] = run; run += d; }
  if (t == 1023) offs[NN] = run;
}

__global__ void fill_kernel(const int* __restrict__ ei, int* __restrict__ cursor,
                            int* __restrict__ elist) {
  int tid = blockIdx.x * 256 + threadIdx.x;
  if (tid < EE) {
    int r = ei[tid];
    int pos = atomicAdd(&cursor[r], 1);
    elist[pos] = tid;
  }
}

// ---------------- edge MLP: swapped-operand, 512 thr / 8 waves, (512,2) — R8-proven ----------------
__global__ __launch_bounds__(512, 2) void edge_mlp_kernel(
    const f16* __restrict__ xh, const float* __restrict__ ea,
    const f16* __restrict__ uh, const int* __restrict__ ei,
    const int* __restrict__ batch,
    const f16* __restrict__ w1t, const f16* __restrict__ w2t, const f16* __restrict__ w3t,
    const float* __restrict__ b1, const float* __restrict__ b2, const float* __restrict__ b3,
    float* __restrict__ e_out)
{
  __shared__ __align__(16) f16 sm[ELDS];
  const int t = threadIdx.x;
  for (int c = t; c < 4096; c += 512) { int r = c >> 5, kc = c & 31;
    *(uint4*)&sm[EW1_OFF + r*EW1_RL + kc*8] = *(const uint4*)&w1t[r*256 + kc*8]; }
  for (int c = t; c < 2048; c += 512) { int r = c >> 4, kc = c & 15;
    *(uint4*)&sm[EW2_OFF + r*136 + kc*8] = *(const uint4*)&w2t[r*128 + kc*8]; }
  for (int c = t; c < 1024; c += 512) { int r = c >> 4, kc = c & 15;
    *(uint4*)&sm[EW3_OFF + r*136 + kc*8] = *(const uint4*)&w3t[r*128 + kc*8]; }
  float* bias = (float*)&sm[EB_OFF];
  if (t < 128) { bias[t] = b1[t]; bias[128 + t] = b2[t]; }
  else if (t < 192) { bias[256 + (t - 128)] = b3[t - 128]; }
  __syncthreads();

  const int l = t & 63, w = t >> 6;         // w in 0..7
  const int r15 = l & 15, g = l >> 4;       // r15 = m-lane, g = n-subrow group
  const int hb = EH_OFF + w * (16 * 72);
  const int NT = EE / 256;                  // 6250
  const int stride = gridDim.x;
  const int t0 = blockIdx.x;

  int rC[2], cC[2], bC[2];   // indices for tile T+1
  int rN[2], cN[2], bN[2];   // indices for tile T+2 (arriving)
  f16x8 Bx[2][6];            // next-tile x/u frags in flight (f16, direct frag layout)
  f32x4 Gea[2][2][2];        // next-tile edge_attr in flight (f32)

  auto issueXU = [&](const int (&rr)[2], const int (&cc)[2], const int (&bb)[2]) {
    #pragma unroll
    for (int mt = 0; mt < 2; ++mt) {
      const f16* pr = xh + (size_t)rr[mt] * 64 + g * 8;
      const f16* pc = xh + (size_t)cc[mt] * 64 + g * 8;
      const f16* pu = uh + (size_t)bb[mt] * 64 + g * 8;
      Bx[mt][0] = *(const f16x8*)pr;        Bx[mt][1] = *(const f16x8*)(pr + 32);
      Bx[mt][2] = *(const f16x8*)pc;        Bx[mt][3] = *(const f16x8*)(pc + 32);
      Bx[mt][4] = *(const f16x8*)pu;        Bx[mt][5] = *(const f16x8*)(pu + 32);
    }
  };
  auto issueEA = [&](int tt) {
    #pragma unroll
    for (int mt = 0; mt < 2; ++mt) {
      const float* pe = ea + ((size_t)(tt * 256 + w * 32 + mt * 16 + r15)) * 64 + g * 8;
      #pragma unroll
      for (int ss = 0; ss < 2; ++ss) {
        Gea[mt][ss][0] = *(const f32x4*)(pe + ss * 32);
        Gea[mt][ss][1] = *(const f32x4*)(pe + ss * 32 + 4);
      }
    }
  };

  // prologue
  {
    int rr[2], cc[2], bb[2];
    #pragma unroll
    for (int mt = 0; mt < 2; ++mt) {
      const int eid = t0 * 256 + w * 32 + mt * 16 + r15;
      rr[mt] = ei[eid]; cc[mt] = ei[EE + eid];
    }
    #pragma unroll
    for (int mt = 0; mt < 2; ++mt) bb[mt] = batch[rr[mt]];
    issueXU(rr, cc, bb); issueEA(t0);
    int t1 = t0 + stride; if (t1 >= NT) t1 = t0;
    #pragma unroll
    for (int mt = 0; mt < 2; ++mt) {
      const int eid = t1 * 256 + w * 32 + mt * 16 + r15;
      rC[mt] = ei[eid]; cC[mt] = ei[EE + eid];
    }
    #pragma unroll
    for (int mt = 0; mt < 2; ++mt) bC[mt] = batch[rC[mt]];
  }

  for (int tile = t0; tile < NT; tile += stride) {
    // ---- assemble data frags (B-operand) for THIS tile ----
    f16x8 A[2][8];
    #pragma unroll
    for (int mt = 0; mt < 2; ++mt) {
      A[mt][0] = Bx[mt][0]; A[mt][1] = Bx[mt][1];
      A[mt][2] = Bx[mt][2]; A[mt][3] = Bx[mt][3];
      A[mt][4] = cvt8(Gea[mt][0][0], Gea[mt][0][1]);
      A[mt][5] = cvt8(Gea[mt][1][0], Gea[mt][1][1]);
      A[mt][6] = Bx[mt][4]; A[mt][7] = Bx[mt][5];
    }

    // prefetch ei for T+2 (cheap, long cover)
    int t2 = tile + 2 * stride; if (t2 >= NT) t2 = t0;
    #pragma unroll
    for (int mt = 0; mt < 2; ++mt) {
      const int eid = t2 * 256 + w * 32 + mt * 16 + r15;
      rN[mt] = ei[eid]; cN[mt] = ei[EE + eid];
    }

    // ---- layer 1 (swapped): D1[n1][m], n1=128 (8 a-tiles), K=256 ----
    f32x4 acc1[2][8];
    #pragma unroll
    for (int a = 0; a < 8; ++a) {
      const f32x4 bv = *(const f32x4*)&bias[a*16 + g*4];
      acc1[0][a] = bv; acc1[1][a] = bv;
    }
    #pragma unroll
    for (int s = 0; s < 8; ++s)
      #pragma unroll
      for (int a = 0; a < 8; ++a) {
        const f16x8 wf = *(const f16x8*)&sm[EW1_OFF + (a*16 + r15)*EW1_RL + s*32 + g*8];
        acc1[0][a] = MFMA16(wf, A[0][s], acc1[0][a]);
        acc1[1][a] = MFMA16(wf, A[1][s], acc1[1][a]);
      }

    // batch for T+2 (rN arrived during layer 1)
    #pragma unroll
    for (int mt = 0; mt < 2; ++mt) bN[mt] = batch[rN[mt]];

    // ---- dance 1: packed b64 writes, per (mt, hh) pass -> B2 frags ----
    f16x8 B2[2][4];
    #pragma unroll
    for (int mt = 0; mt < 2; ++mt)
      #pragma unroll
      for (int hh = 0; hh < 2; ++hh) {
        #pragma unroll
        for (int ap = 0; ap < 4; ++ap) {
          const f32x4 v = acc1[mt][hh*4 + ap];
          f16x4 hv;
          hv[0]=(f16)fmaxf(v[0],0.f); hv[1]=(f16)fmaxf(v[1],0.f);
          hv[2]=(f16)fmaxf(v[2],0.f); hv[3]=(f16)fmaxf(v[3],0.f);
          *(f16x4*)&sm[hb + r15*72 + ap*16 + g*4] = hv;
        }
        #pragma unroll
        for (int sl = 0; sl < 2; ++sl)
          B2[mt][hh*2 + sl] = *(const f16x8*)&sm[hb + r15*72 + sl*32 + g*8];
      }

    // issue next tile's x/u loads (covered by layers 2-3)
    int t1 = tile + stride; if (t1 >= NT) t1 = t0;
    issueXU(rC, cC, bC);

    // ---- layer 2 (swapped): n2=128, K=128 ----
    f32x4 acc2[2][8];
    #pragma unroll
    for (int a = 0; a < 8; ++a) {
      const f32x4 bv = *(const f32x4*)&bias[128 + a*16 + g*4];
      acc2[0][a] = bv; acc2[1][a] = bv;
    }
    #pragma unroll
    for (int s = 0; s < 4; ++s)
      #pragma unroll
      for (int a = 0; a < 8; ++a) {
        const f16x8 wf = *(const f16x8*)&sm[EW2_OFF + (a*16 + r15)*136 + s*32 + g*8];
        acc2[0][a] = MFMA16(wf, B2[0][s], acc2[0][a]);
        acc2[1][a] = MFMA16(wf, B2[1][s], acc2[1][a]);
      }

    // ---- dance 2 -> B3 frags ----
    f16x8 B3[2][4];
    #pragma unroll
    for (int mt = 0; mt < 2; ++mt)
      #pragma unroll
      for (int hh = 0; hh < 2; ++hh) {
        #pragma unroll
        for (int ap = 0; ap < 4; ++ap) {
          const f32x4 v = acc2[mt][hh*4 + ap];
          f16x4 hv;
          hv[0]=(f16)fmaxf(v[0],0.f); hv[1]=(f16)fmaxf(v[1],0.f);
          hv[2]=(f16)fmaxf(v[2],0.f); hv[3]=(f16)fmaxf(v[3],0.f);
          *(f16x4*)&sm[hb + r15*72 + ap*16 + g*4] = hv;
        }
        #pragma unroll
        for (int sl = 0; sl < 2; ++sl)
          B3[mt][hh*2 + sl] = *(const f16x8*)&sm[hb + r15*72 + sl*32 + g*8];
      }

    // issue next tile's ea loads (covered by layer 3 + store)
    issueEA(t1);

    // ---- layer 3 (swapped): n3=64, K=128 ----
    f32x4 acc3[2][4];
    #pragma unroll
    for (int a = 0; a < 4; ++a) {
      const f32x4 bv = *(const f32x4*)&bias[256 + a*16 + g*4];
      acc3[0][a] = bv; acc3[1][a] = bv;
    }
    #pragma unroll
    for (int s = 0; s < 4; ++s)
      #pragma unroll
      for (int a = 0; a < 4; ++a) {
        const f16x8 wf = *(const f16x8*)&sm[EW3_OFF + (a*16 + r15)*136 + s*32 + g*8];
        acc3[0][a] = MFMA16(wf, B3[0][s], acc3[0][a]);
        acc3[1][a] = MFMA16(wf, B3[1][s], acc3[1][a]);
      }

    // ---- epilogue: vector stores (lane holds e[m][16a+4g .. +3]) ----
    const int base = tile * 256 + w * 32;
    #pragma unroll
    for (int mt = 0; mt < 2; ++mt) {
      const int m = base + mt * 16 + r15;
      #pragma unroll
      for (int a = 0; a < 4; ++a)
        *(f32x4*)&e_out[(size_t)m * 64 + a*16 + g*4] = acc3[mt][a];
    }

    #pragma unroll
    for (int mt = 0; mt < 2; ++mt) { rC[mt] = rN[mt]; cC[mt] = cN[mt]; bC[mt] = bN[mt]; }
  }
}

// ---------------- n_agg sums via CSR gather (16-deep ILP) ----------------
__global__ void nsum_kernel(const float* __restrict__ e_src, const int* __restrict__ offs,
                            const int* __restrict__ elist, float* __restrict__ n_sum) {
  const int l = threadIdx.x & 63;
  const int wid = (blockIdx.x * blockDim.x + threadIdx.x) >> 6;
  const int nw = (gridDim.x * blockDim.x) >> 6;
  for (int node = wid; node < NN; node += nw) {
    const int s = offs[node], e = offs[node + 1];
    float acc = 0.f;
    int j = s;
    for (; j + 16 <= e; j += 16) {
      float v[16];
      #pragma unroll
      for (int k = 0; k < 16; ++k) v[k] = e_src[(size_t)elist[j + k] * 64 + l];
      float s0 = ((v[0]+v[1])+(v[2]+v[3])) + ((v[4]+v[5])+(v[6]+v[7]));
      float s1 = ((v[8]+v[9])+(v[10]+v[11])) + ((v[12]+v[13])+(v[14]+v[15]));
      acc += s0 + s1;
    }
    for (; j + 4 <= e; j += 4) {
      float v0 = e_src[(size_t)elist[j]   * 64 + l];
      float v1 = e_src[(size_t)elist[j+1] * 64 + l];
      float v2 = e_src[(size_t)elist[j+2] * 64 + l];
      float v3 = e_src[(size_t)elist[j+3] * 64 + l];
      acc += (v0 + v1) + (v2 + v3);
    }
    for (; j < e; ++j) acc += e_src[(size_t)elist[j] * 64 + l];
    n_sum[(size_t)node * 64 + l] = acc;
  }
}

// ---------------- node MLP (persistent) ----------------
__global__ __launch_bounds__(256, 1) void node_mlp_kernel(
    const float* __restrict__ x, const float* __restrict__ u,
    const int* __restrict__ batch, const float* __restrict__ n_sum,
    const int* __restrict__ deg,
    const f16* __restrict__ w1t, const f16* __restrict__ w2t, const f16* __restrict__ w3t,
    const float* __restrict__ b1, const float* __restrict__ b2, const float* __restrict__ b3,
    float* __restrict__ xn_out)
{
  __shared__ __align__(16) f16 sm[NLDS];
  const int t = threadIdx.x;
  for (int c = t; c < 3072; c += 256) { int r = c / 24, kc = c - r * 24;
    *(uint4*)&sm[NW1_OFF + r*NW1_RL + kc*8] = *(const uint4*)&w1t[r*192 + kc*8]; }
  for (int c = t; c < 2048; c += 256) { int r = c >> 4, kc = c & 15;
    *(uint4*)&sm[NW2_OFF + r*136 + kc*8] = *(const uint4*)&w2t[r*128 + kc*8]; }
  for (int c = t; c < 1024; c += 256) { int r = c >> 4, kc = c & 15;
    *(uint4*)&sm[NW3_OFF + r*136 + kc*8] = *(const uint4*)&w3t[r*128 + kc*8]; }
  float* bias = (float*)&sm[NB_OFF];
  if (t < 128) { bias[t] = b1[t]; bias[128 + t] = b2[t]; }
  if (t < 64)  { bias[256 + t] = b3[t]; }
  __syncthreads();

  const int l = t & 63, w = t >> 6;
  const int r15 = l & 15, g = l >> 4;
  const int hb = NH_OFF + w * (32 * 136);
  const int NTT = (NN + 127) / 128;   // 391

  for (int tile = blockIdx.x; tile < NTT; tile += gridDim.x) {
    const int base = tile * 128 + w * 32;
    f16x8 A1[2][6];
    #pragma unroll
    for (int mt = 0; mt < 2; ++mt) {
      int raw = base + mt * 16 + r15;
      int node = raw < NN ? raw : NN - 1;
      float inv = 1.0f / fmaxf((float)deg[node], 1.0f);
      const float* sA = n_sum + (size_t)node * 64;
      const float* sB = x + (size_t)node * 64;
      const float* sC = u + (size_t)batch[node] * 64;
      #pragma unroll
      for (int s = 0; s < 6; ++s) {
        const int off = (s & 1) * 32 + g * 8;
        if (s < 2)      A1[mt][s] = pack8s(sA + off, inv);
        else if (s < 4) A1[mt][s] = pack8(sB + off);
        else            A1[mt][s] = pack8(sC + off);
      }
    }
    f32x4 acc3[2][4];
    mlp3_core<6, NW1_RL, NW1_OFF, NW2_OFF, NW3_OFF>(sm, bias, bias + 128, bias + 256,
                                                    A1, hb, r15, g, acc3);
    #pragma unroll
    for (int mt = 0; mt < 2; ++mt)
      #pragma unroll
      for (int nt = 0; nt < 4; ++nt)
        #pragma unroll
        for (int i = 0; i < 4; ++i) {
          const int m = base + mt * 16 + g * 4 + i;
          if (m < NN) xn_out[(size_t)m * 64 + nt * 16 + r15] = acc3[mt][nt][i];
        }
  }
}

// ---------------- per-batch segmented sums ----------------
__global__ void batch_sum_kernel(const float* __restrict__ xn, const float* __restrict__ n_sum,
                                 const int* __restrict__ deg, const int* __restrict__ bstart,
                                 float* __restrict__ nbsum, float* __restrict__ ebsum,
                                 int* __restrict__ ncnt, int* __restrict__ ecnt) {
  __shared__ float red0[256];
  __shared__ float red1[256];
  __shared__ int   redi[256];
  const int b = blockIdx.x;
  const int s = bstart[b], e = bstart[b + 1];
  const int t = threadIdx.x, c = t & 63, j0 = t >> 6;
  float xs = 0.f, ns = 0.f; int dc = 0;
  for (int j = s + j0; j < e; j += 4) {
    xs += xn[(size_t)j * 64 + c];
    ns += n_sum[(size_t)j * 64 + c];
    if (c == 0) dc += deg[j];
  }
  red0[t] = xs; red1[t] = ns; redi[t] = dc;
  __syncthreads();
  if (t < 128) { red0[t] += red0[t + 128]; red1[t] += red1[t + 128]; redi[t] += redi[t + 128]; }
  __syncthreads();
  if (t < 64) {
    float a0 = red0[t] + red0[t + 64];
    float a1 = red1[t] + red1[t + 64];
    nbsum[b * 64 + t] = a0;
    ebsum[b * 64 + t] = a1;
    if (t == 0) { ncnt[b] = e - s; ecnt[b] = redi[0] + redi[64]; }
  }
}

// ---------------- global MLP ----------------
__global__ __launch_bounds__(256, 1) void global_mlp_kernel(
    const float* __restrict__ u, const float* __restrict__ nbsum,
    const float* __restrict__ ebsum, const int* __restrict__ ncnt,
    const int* __restrict__ ecnt,
    const f16* __restrict__ w1t, const f16* __restrict__ w2t, const f16* __restrict__ w3t,
    const float* __restrict__ b1, const float* __restrict__ b2, const float* __restrict__ b3,
    float* __restrict__ un_out)
{
  __shared__ __align__(16) f16 sm[NLDS];
  const int t = threadIdx.x;
  for (int c = t; c < 3072; c += 256) { int r = c / 24, kc = c - r * 24;
    *(uint4*)&sm[NW1_OFF + r*NW1_RL + kc*8] = *(const uint4*)&w1t[r*192 + kc*8]; }
  for (int c = t; c < 2048; c += 256) { int r = c >> 4, kc = c & 15;
    *(uint4*)&sm[NW2_OFF + r*136 + kc*8] = *(const uint4*)&w2t[r*128 + kc*8]; }
  for (int c = t; c < 1024; c += 256) { int r = c >> 4, kc = c & 15;
    *(uint4*)&sm[NW3_OFF + r*136 + kc*8] = *(const uint4*)&w3t[r*128 + kc*8]; }
  float* bias = (float*)&sm[NB_OFF];
  if (t < 128) { bias[t] = b1[t]; bias[128 + t] = b2[t]; }
  if (t < 64)  { bias[256 + t] = b3[t]; }
  __syncthreads();

  const int l = t & 63, w = t >> 6;
  const int r15 = l & 15, g = l >> 4;
  const int hb = NH_OFF + w * (32 * 136);
  const int base = blockIdx.x * 128 + w * 32;

  f16x8 A1[2][6];
  #pragma unroll
  for (int mt = 0; mt < 2; ++mt) {
    const int r = base + mt * 16 + r15;
    const float invn = 1.0f / fmaxf((float)ncnt[r], 1.0f);
    const float inve = 1.0f / fmaxf((float)ecnt[r], 1.0f);
    const float* sA = u + (size_t)r * 64;
    const float* sB = nbsum + (size_t)r * 64;
    const float* sC = ebsum + (size_t)r * 64;
    #pragma unroll
    for (int s = 0; s < 6; ++s) {
      const int off = (s & 1) * 32 + g * 8;
      if (s < 2)      A1[mt][s] = pack8(sA + off);
      else if (s < 4) A1[mt][s] = pack8s(sB + off, invn);
      else            A1[mt][s] = pack8s(sC + off, inve);
    }
  }
  f32x4 acc3[2][4];
  mlp3_core<6, NW1_RL, NW1_OFF, NW2_OFF, NW3_OFF>(sm, bias, bias + 128, bias + 256,
                                                  A1, hb, r15, g, acc3);
  #pragma unroll
  for (int mt = 0; mt < 2; ++mt)
    #pragma unroll
    for (int nt = 0; nt < 4; ++nt)
      #pragma unroll
      for (int i = 0; i < 4; ++i) {
        const int m = base + mt * 16 + g * 4 + i;
        un_out[(size_t)m * 64 + nt * 16 + r15] = acc3[mt][nt][i];
      }
}

// ---------------- host launcher ----------------
extern "C" void kernel_launch(void* const* d_in, const int* in_sizes, int n_in,
                              void* d_out, int out_size, void* d_ws, size_t ws_size,
                              hipStream_t stream)
{
  (void)in_sizes; (void)n_in; (void)out_size; (void)ws_size;
  const float* x     = (const float*)d_in[0];
  const float* ea    = (const float*)d_in[1];
  const float* u     = (const float*)d_in[2];
  const int*   ei    = (const int*)d_in[3];
  const int*   batch = (const int*)d_in[4];
  const float* ew1 = (const float*)d_in[5];  const float* eb1 = (const float*)d_in[6];
  const float* ew2 = (const float*)d_in[7];  const float* eb2 = (const float*)d_in[8];
  const float* ew3 = (const float*)d_in[9];  const float* eb3 = (const float*)d_in[10];
  const float* nw1 = (const float*)d_in[11]; const float* nb1 = (const float*)d_in[12];
  const float* nw2 = (const float*)d_in[13]; const float* nb2 = (const float*)d_in[14];
  const float* nw3 = (const float*)d_in[15]; const float* nb3 = (const float*)d_in[16];
  const float* gw1 = (const float*)d_in[17]; const float* gb1 = (const float*)d_in[18];
  const float* gw2 = (const float*)d_in[19]; const float* gb2 = (const float*)d_in[20];
  const float* gw3 = (const float*)d_in[21]; const float* gb3 = (const float*)d_in[22];

  float* xn_out = (float*)d_out;
  float* e_out  = xn_out + (size_t)NN * DD;
  float* un_out = e_out + (size_t)EE * DD;

  char* p = (char*)d_ws;
  auto alloc = [&](size_t bytes) -> void* {
    void* r = (void*)p; p += (bytes + 255) & ~(size_t)255; return r;
  };
  // NOTE: 9 weight buffers must stay contiguous in this order (prep writes linearly)
  f16* wtE1 = (f16*)alloc(256 * 128 * 2);
  f16* wtE2 = (f16*)alloc(128 * 128 * 2);
  f16* wtE3 = (f16*)alloc(128 * 64 * 2);
  f16* wtN1 = (f16*)alloc(192 * 128 * 2);
  f16* wtN2 = (f16*)alloc(128 * 128 * 2);
  f16* wtN3 = (f16*)alloc(128 * 64 * 2);
  f16* wtG1 = (f16*)alloc(192 * 128 * 2);
  f16* wtG2 = (f16*)alloc(128 * 128 * 2);
  f16* wtG3 = (f16*)alloc(128 * 64 * 2);
  int* deg    = (int*)alloc((size_t)NN * 4);
  int* offs   = (int*)alloc((size_t)(NN + 1) * 4);
  int* cursor = (int*)alloc((size_t)NN * 4);
  int* elist  = (int*)alloc((size_t)EE * 4);
  int* bstart = (int*)alloc((size_t)(BBATCH + 1) * 4);
  float* nbsum = (float*)alloc((size_t)BBATCH * 64 * 4);
  float* ebsum = (float*)alloc((size_t)BBATCH * 64 * 4);
  int* ncnt = (int*)alloc((size_t)BBATCH * 4);
  int* ecnt = (int*)alloc((size_t)BBATCH * 4);
  float* n_sum = (float*)alloc((size_t)NN * 64 * 4);
  f16* xh = (f16*)alloc((size_t)NN * 64 * 2);
  f16* uh = (f16*)alloc((size_t)BBATCH * 64 * 2);

  hipMemsetAsync(deg, 0, (size_t)NN * 4, stream);
  prep_kernel<<<dim3(6250), dim3(256), 0, stream>>>(
      ew1, ew2, ew3, nw1, nw2, nw3, gw1, gw2, gw3, wtE1,
      x, u, xh, uh, ei, deg, batch, bstart);
  scan_kernel<<<dim3(1), dim3(1024), 0, stream>>>(deg, offs, cursor);
  fill_kernel<<<dim3(6250), dim3(256), 0, stream>>>(ei, cursor, elist);

  edge_mlp_kernel<<<dim3(256), dim3(512), 0, stream>>>(
      xh, ea, uh, ei, batch, wtE1, wtE2, wtE3, eb1, eb2, eb3, e_out);

  nsum_kernel<<<dim3(4096), dim3(256), 0, stream>>>(e_out, offs, elist, n_sum);

  node_mlp_kernel<<<dim3(256), dim3(256), 0, stream>>>(
      x, u, batch, n_sum, deg, wtN1, wtN2, wtN3, nb1, nb2, nb3, xn_out);

  batch_sum_kernel<<<dim3(BBATCH), dim3(256), 0, stream>>>(
      xn_out, n_sum, deg, bstart, nbsum, ebsum, ncnt, ecnt);

  global_mlp_kernel<<<dim3(2), dim3(256), 0, stream>>>(
      u, nbsum, ebsum, ncnt, ecnt, wtG1, wtG2, wtG3, gb1, gb2, gb3, un_out);
}

// Round 13
// 727.842 us; speedup vs baseline: 1.5150x; 1.0047x over previous
//
#include <hip/hip_runtime.h>

#define NN 50000
#define EE 1600000
#define BBATCH 256
#define DD 64

typedef _Float16 f16;
typedef _Float16 f16x4 __attribute__((ext_vector_type(4)));
typedef _Float16 f16x8 __attribute__((ext_vector_type(8)));
typedef float f32x4 __attribute__((ext_vector_type(4)));

#define MFMA16(a,b,c) __builtin_amdgcn_mfma_f32_16x16x32_f16((a),(b),(c),0,0,0)

// ---------------- LDS layouts (in halves) ----------------
// Edge kernel (512 thr / 8 waves, R8-proven): W1 [128][256->264], W2 [128][136], W3 [64][136],
// h 8x[16][72], bias 320 f32. Total 139520 B.
constexpr int EW1_RL  = 264;
constexpr int EW1_OFF = 0;
constexpr int EW2_OFF = EW1_OFF + 128 * EW1_RL;   // 33792
constexpr int EW3_OFF = EW2_OFF + 128 * 136;      // 51200
constexpr int EH_OFF  = EW3_OFF + 64 * 136;       // 59904
constexpr int EB_OFF  = EH_OFF + 8 * 16 * 72;     // 69120
constexpr int ELDS    = EB_OFF + 640;             // 69760 halves = 139520 B

// Node/global kernel (256 thr / 4 waves).
constexpr int NW1_RL  = 200;
constexpr int NW1_OFF = 0;
constexpr int NW2_OFF = NW1_OFF + 128 * NW1_RL;   // 25600
constexpr int NW3_OFF = NW2_OFF + 128 * 136;      // 43008
constexpr int NH_OFF  = NW3_OFF + 64 * 136;       // 51712
constexpr int NB_OFF  = NH_OFF + 4 * 32 * 136;    // 69120
constexpr int NLDS    = NB_OFF + 640;             // 69760 halves = 139520 B

// ---------------- helpers ----------------
__device__ __forceinline__ f16x8 pack8(const float* __restrict__ p) {
  f32x4 a = *(const f32x4*)p;
  f32x4 b = *(const f32x4*)(p + 4);
  f16x8 r;
  r[0]=(f16)a[0]; r[1]=(f16)a[1]; r[2]=(f16)a[2]; r[3]=(f16)a[3];
  r[4]=(f16)b[0]; r[5]=(f16)b[1]; r[6]=(f16)b[2]; r[7]=(f16)b[3];
  return r;
}
__device__ __forceinline__ f16x8 pack8s(const float* __restrict__ p, float sc) {
  f32x4 a = *(const f32x4*)p;
  f32x4 b = *(const f32x4*)(p + 4);
  a = a * sc; b = b * sc;
  f16x8 r;
  r[0]=(f16)a[0]; r[1]=(f16)a[1]; r[2]=(f16)a[2]; r[3]=(f16)a[3];
  r[4]=(f16)b[0]; r[5]=(f16)b[1]; r[6]=(f16)b[2]; r[7]=(f16)b[3];
  return r;
}
__device__ __forceinline__ f16x8 cvt8(f32x4 a, f32x4 b) {
  f16x8 r;
  r[0]=(f16)a[0]; r[1]=(f16)a[1]; r[2]=(f16)a[2]; r[3]=(f16)a[3];
  r[4]=(f16)b[0]; r[5]=(f16)b[1]; r[6]=(f16)b[2]; r[7]=(f16)b[3];
  return r;
}

// 3-layer MLP core for node/global kernels (4-wave, h [32][136], unswapped; proven).
template<int KSL, int W1RL, int W1O, int W2O, int W3O>
__device__ __forceinline__ void mlp3_core(f16* __restrict__ sm,
    const float* __restrict__ b1l, const float* __restrict__ b2l,
    const float* __restrict__ b3l,
    const f16x8 (&A1)[2][KSL], const int hb, const int r15, const int g,
    f32x4 (&acc3)[2][4])
{
  #pragma unroll
  for (int hh = 0; hh < 2; ++hh) {
    f32x4 acc[2][4];
    #pragma unroll
    for (int nt = 0; nt < 4; ++nt) {
      const float bv = b1l[(hh*4 + nt)*16 + r15];
      acc[0][nt] = (f32x4){bv, bv, bv, bv};
      acc[1][nt] = acc[0][nt];
    }
    #pragma unroll
    for (int s = 0; s < KSL; ++s) {
      #pragma unroll
      for (int nt = 0; nt < 4; ++nt) {
        const f16x8 bf = *(const f16x8*)&sm[W1O + ((hh*4+nt)*16 + r15) * W1RL + s*32 + g*8];
        acc[0][nt] = MFMA16(A1[0][s], bf, acc[0][nt]);
        acc[1][nt] = MFMA16(A1[1][s], bf, acc[1][nt]);
      }
    }
    #pragma unroll
    for (int mt = 0; mt < 2; ++mt)
      #pragma unroll
      for (int nt = 0; nt < 4; ++nt)
        #pragma unroll
        for (int i = 0; i < 4; ++i)
          sm[hb + (mt*16 + g*4 + i)*136 + (hh*4+nt)*16 + r15] =
              (f16)fmaxf(acc[mt][nt][i], 0.f);
  }

  f16x8 A2[2][4];
  #pragma unroll
  for (int mt = 0; mt < 2; ++mt)
    #pragma unroll
    for (int s = 0; s < 4; ++s)
      A2[mt][s] = *(const f16x8*)&sm[hb + (mt*16 + r15)*136 + s*32 + g*8];

  #pragma unroll
  for (int hh = 0; hh < 2; ++hh) {
    f32x4 acc[2][4];
    #pragma unroll
    for (int nt = 0; nt < 4; ++nt) {
      const float bv = b2l[(hh*4 + nt)*16 + r15];
      acc[0][nt] = (f32x4){bv, bv, bv, bv};
      acc[1][nt] = acc[0][nt];
    }
    #pragma unroll
    for (int s = 0; s < 4; ++s) {
      #pragma unroll
      for (int nt = 0; nt < 4; ++nt) {
        const f16x8 bf = *(const f16x8*)&sm[W2O + ((hh*4+nt)*16 + r15)*136 + s*32 + g*8];
        acc[0][nt] = MFMA16(A2[0][s], bf, acc[0][nt]);
        acc[1][nt] = MFMA16(A2[1][s], bf, acc[1][nt]);
      }
    }
    #pragma unroll
    for (int mt = 0; mt < 2; ++mt)
      #pragma unroll
      for (int nt = 0; nt < 4; ++nt)
        #pragma unroll
        for (int i = 0; i < 4; ++i)
          sm[hb + (mt*16 + g*4 + i)*136 + (hh*4+nt)*16 + r15] =
              (f16)fmaxf(acc[mt][nt][i], 0.f);
  }

  f16x8 A3[2][4];
  #pragma unroll
  for (int mt = 0; mt < 2; ++mt)
    #pragma unroll
    for (int s = 0; s < 4; ++s)
      A3[mt][s] = *(const f16x8*)&sm[hb + (mt*16 + r15)*136 + s*32 + g*8];

  #pragma unroll
  for (int nt = 0; nt < 4; ++nt) {
    const float bv = b3l[nt*16 + r15];
    acc3[0][nt] = (f32x4){bv, bv, bv, bv};
    acc3[1][nt] = acc3[0][nt];
  }
  #pragma unroll
  for (int s = 0; s < 4; ++s) {
    #pragma unroll
    for (int nt = 0; nt < 4; ++nt) {
      const f16x8 bf = *(const f16x8*)&sm[W3O + (nt*16 + r15)*136 + s*32 + g*8];
      acc3[0][nt] = MFMA16(A3[0][s], bf, acc3[0][nt]);
      acc3[1][nt] = MFMA16(A3[1][s], bf, acc3[1][nt]);
    }
  }
}

// ---------------- fused prep: 9 transposes + x/u f16 cvt + deg count + bstart ----------------
__global__ void prep_kernel(
    const float* __restrict__ e1, const float* __restrict__ e2, const float* __restrict__ e3,
    const float* __restrict__ n1, const float* __restrict__ n2, const float* __restrict__ n3,
    const float* __restrict__ q1, const float* __restrict__ q2, const float* __restrict__ q3,
    f16* __restrict__ wdst,
    const float* __restrict__ x, const float* __restrict__ u,
    f16* __restrict__ xh, f16* __restrict__ uh,
    const int* __restrict__ ei, int* __restrict__ deg,
    const int* __restrict__ batch, int* __restrict__ bstart)
{
  const int tid = blockIdx.x * 256 + threadIdx.x;

  // job 1: weight transposes (155648 elems)
  {
    const int o1=32768,o2=49152,o3=57344,o4=81920,o5=98304,o6=106496,o7=131072,o8=147456,o9=155648;
    if (tid < o9) {
      const float* src; int in, od, rel;
      if      (tid < o1) { src=e1; in=256; od=128; rel=tid;    }
      else if (tid < o2) { src=e2; in=128; od=128; rel=tid-o1; }
      else if (tid < o3) { src=e3; in=128; od=64;  rel=tid-o2; }
      else if (tid < o4) { src=n1; in=192; od=128; rel=tid-o3; }
      else if (tid < o5) { src=n2; in=128; od=128; rel=tid-o4; }
      else if (tid < o6) { src=n3; in=128; od=64;  rel=tid-o5; }
      else if (tid < o7) { src=q1; in=192; od=128; rel=tid-o6; }
      else if (tid < o8) { src=q2; in=128; od=128; rel=tid-o7; }
      else               { src=q3; in=128; od=64;  rel=tid-o8; }
      int o = rel / in, i = rel - o * in;
      wdst[tid] = (f16)src[(size_t)i * od + o];
    }
  }

  // job 2: x -> xh, u -> uh
  if (tid < NN * 64 / 4) {
    f32x4 v = *(const f32x4*)&x[(size_t)tid * 4];
    f16x4 h; h[0]=(f16)v[0]; h[1]=(f16)v[1]; h[2]=(f16)v[2]; h[3]=(f16)v[3];
    *(f16x4*)&xh[(size_t)tid * 4] = h;
  }
  if (tid < BBATCH * 64 / 4) {
    f32x4 v = *(const f32x4*)&u[(size_t)tid * 4];
    f16x4 h; h[0]=(f16)v[0]; h[1]=(f16)v[1]; h[2]=(f16)v[2]; h[3]=(f16)v[3];
    *(f16x4*)&uh[(size_t)tid * 4] = h;
  }

  // job 3: degree count
  if (tid < EE) atomicAdd(&deg[ei[tid]], 1);

  // job 4: batch segment starts (batch sorted)
  if (tid < NN) {
    int b = batch[tid];
    if (tid == 0) { for (int k = 0; k <= b; ++k) bstart[k] = 0; }
    else { int pb = batch[tid - 1]; for (int k = pb + 1; k <= b; ++k) bstart[k] = tid; }
    if (tid == NN - 1) { for (int k = b + 1; k <= BBATCH; ++k) bstart[k] = NN; }
  }
}

// ---------------- edge MLP: swapped-operand, 512 thr / 8 waves, (512,2) — R8-proven ----------------
__global__ __launch_bounds__(512, 2) void edge_mlp_kernel(
    const f16* __restrict__ xh, const float* __restrict__ ea,
    const f16* __restrict__ uh, const int* __restrict__ ei,
    const int* __restrict__ batch,
    const f16* __restrict__ w1t, const f16* __restrict__ w2t, const f16* __restrict__ w3t,
    const float* __restrict__ b1, const float* __restrict__ b2, const float* __restrict__ b3,
    float* __restrict__ e_out)
{
  __shared__ __align__(16) f16 sm[ELDS];
  const int t = threadIdx.x;
  for (int c = t; c < 4096; c += 512) { int r = c >> 5, kc = c & 31;
    *(uint4*)&sm[EW1_OFF + r*EW1_RL + kc*8] = *(const uint4*)&w1t[r*256 + kc*8]; }
  for (int c = t; c < 2048; c += 512) { int r = c >> 4, kc = c & 15;
    *(uint4*)&sm[EW2_OFF + r*136 + kc*8] = *(const uint4*)&w2t[r*128 + kc*8]; }
  for (int c = t; c < 1024; c += 512) { int r = c >> 4, kc = c & 15;
    *(uint4*)&sm[EW3_OFF + r*136 + kc*8] = *(const uint4*)&w3t[r*128 + kc*8]; }
  float* bias = (float*)&sm[EB_OFF];
  if (t < 128) { bias[t] = b1[t]; bias[128 + t] = b2[t]; }
  else if (t < 192) { bias[256 + (t - 128)] = b3[t - 128]; }
  __syncthreads();

  const int l = t & 63, w = t >> 6;         // w in 0..7
  const int r15 = l & 15, g = l >> 4;       // r15 = m-lane, g = n-subrow group
  const int hb = EH_OFF + w * (16 * 72);
  const int NT = EE / 256;                  // 6250
  const int stride = gridDim.x;
  const int t0 = blockIdx.x;

  int rC[2], cC[2], bC[2];   // indices for tile T+1
  int rN[2], cN[2], bN[2];   // indices for tile T+2 (arriving)
  f16x8 Bx[2][6];            // next-tile x/u frags in flight (f16, direct frag layout)
  f32x4 Gea[2][2][2];        // next-tile edge_attr in flight (f32)

  auto issueXU = [&](const int (&rr)[2], const int (&cc)[2], const int (&bb)[2]) {
    #pragma unroll
    for (int mt = 0; mt < 2; ++mt) {
      const f16* pr = xh + (size_t)rr[mt] * 64 + g * 8;
      const f16* pc = xh + (size_t)cc[mt] * 64 + g * 8;
      const f16* pu = uh + (size_t)bb[mt] * 64 + g * 8;
      Bx[mt][0] = *(const f16x8*)pr;        Bx[mt][1] = *(const f16x8*)(pr + 32);
      Bx[mt][2] = *(const f16x8*)pc;        Bx[mt][3] = *(const f16x8*)(pc + 32);
      Bx[mt][4] = *(const f16x8*)pu;        Bx[mt][5] = *(const f16x8*)(pu + 32);
    }
  };
  auto issueEA = [&](int tt) {
    #pragma unroll
    for (int mt = 0; mt < 2; ++mt) {
      const float* pe = ea + ((size_t)(tt * 256 + w * 32 + mt * 16 + r15)) * 64 + g * 8;
      #pragma unroll
      for (int ss = 0; ss < 2; ++ss) {
        Gea[mt][ss][0] = *(const f32x4*)(pe + ss * 32);
        Gea[mt][ss][1] = *(const f32x4*)(pe + ss * 32 + 4);
      }
    }
  };

  // prologue
  {
    int rr[2], cc[2], bb[2];
    #pragma unroll
    for (int mt = 0; mt < 2; ++mt) {
      const int eid = t0 * 256 + w * 32 + mt * 16 + r15;
      rr[mt] = ei[eid]; cc[mt] = ei[EE + eid];
    }
    #pragma unroll
    for (int mt = 0; mt < 2; ++mt) bb[mt] = batch[rr[mt]];
    issueXU(rr, cc, bb); issueEA(t0);
    int t1 = t0 + stride; if (t1 >= NT) t1 = t0;
    #pragma unroll
    for (int mt = 0; mt < 2; ++mt) {
      const int eid = t1 * 256 + w * 32 + mt * 16 + r15;
      rC[mt] = ei[eid]; cC[mt] = ei[EE + eid];
    }
    #pragma unroll
    for (int mt = 0; mt < 2; ++mt) bC[mt] = batch[rC[mt]];
  }

  for (int tile = t0; tile < NT; tile += stride) {
    // ---- assemble data frags (B-operand) for THIS tile ----
    f16x8 A[2][8];
    #pragma unroll
    for (int mt = 0; mt < 2; ++mt) {
      A[mt][0] = Bx[mt][0]; A[mt][1] = Bx[mt][1];
      A[mt][2] = Bx[mt][2]; A[mt][3] = Bx[mt][3];
      A[mt][4] = cvt8(Gea[mt][0][0], Gea[mt][0][1]);
      A[mt][5] = cvt8(Gea[mt][1][0], Gea[mt][1][1]);
      A[mt][6] = Bx[mt][4]; A[mt][7] = Bx[mt][5];
    }

    // prefetch ei for T+2 (cheap, long cover)
    int t2 = tile + 2 * stride; if (t2 >= NT) t2 = t0;
    #pragma unroll
    for (int mt = 0; mt < 2; ++mt) {
      const int eid = t2 * 256 + w * 32 + mt * 16 + r15;
      rN[mt] = ei[eid]; cN[mt] = ei[EE + eid];
    }

    // ---- layer 1 (swapped): D1[n1][m], n1=128 (8 a-tiles), K=256 ----
    f32x4 acc1[2][8];
    #pragma unroll
    for (int a = 0; a < 8; ++a) {
      const f32x4 bv = *(const f32x4*)&bias[a*16 + g*4];
      acc1[0][a] = bv; acc1[1][a] = bv;
    }
    #pragma unroll
    for (int s = 0; s < 8; ++s)
      #pragma unroll
      for (int a = 0; a < 8; ++a) {
        const f16x8 wf = *(const f16x8*)&sm[EW1_OFF + (a*16 + r15)*EW1_RL + s*32 + g*8];
        acc1[0][a] = MFMA16(wf, A[0][s], acc1[0][a]);
        acc1[1][a] = MFMA16(wf, A[1][s], acc1[1][a]);
      }

    // batch for T+2 (rN arrived during layer 1)
    #pragma unroll
    for (int mt = 0; mt < 2; ++mt) bN[mt] = batch[rN[mt]];

    // ---- dance 1: packed b64 writes, per (mt, hh) pass -> B2 frags ----
    f16x8 B2[2][4];
    #pragma unroll
    for (int mt = 0; mt < 2; ++mt)
      #pragma unroll
      for (int hh = 0; hh < 2; ++hh) {
        #pragma unroll
        for (int ap = 0; ap < 4; ++ap) {
          const f32x4 v = acc1[mt][hh*4 + ap];
          f16x4 hv;
          hv[0]=(f16)fmaxf(v[0],0.f); hv[1]=(f16)fmaxf(v[1],0.f);
          hv[2]=(f16)fmaxf(v[2],0.f); hv[3]=(f16)fmaxf(v[3],0.f);
          *(f16x4*)&sm[hb + r15*72 + ap*16 + g*4] = hv;
        }
        #pragma unroll
        for (int sl = 0; sl < 2; ++sl)
          B2[mt][hh*2 + sl] = *(const f16x8*)&sm[hb + r15*72 + sl*32 + g*8];
      }

    // issue next tile's x/u loads (covered by layers 2-3)
    int t1 = tile + stride; if (t1 >= NT) t1 = t0;
    issueXU(rC, cC, bC);

    // ---- layer 2 (swapped): n2=128, K=128 ----
    f32x4 acc2[2][8];
    #pragma unroll
    for (int a = 0; a < 8; ++a) {
      const f32x4 bv = *(const f32x4*)&bias[128 + a*16 + g*4];
      acc2[0][a] = bv; acc2[1][a] = bv;
    }
    #pragma unroll
    for (int s = 0; s < 4; ++s)
      #pragma unroll
      for (int a = 0; a < 8; ++a) {
        const f16x8 wf = *(const f16x8*)&sm[EW2_OFF + (a*16 + r15)*136 + s*32 + g*8];
        acc2[0][a] = MFMA16(wf, B2[0][s], acc2[0][a]);
        acc2[1][a] = MFMA16(wf, B2[1][s], acc2[1][a]);
      }

    // ---- dance 2 -> B3 frags ----
    f16x8 B3[2][4];
    #pragma unroll
    for (int mt = 0; mt < 2; ++mt)
      #pragma unroll
      for (int hh = 0; hh < 2; ++hh) {
        #pragma unroll
        for (int ap = 0; ap < 4; ++ap) {
          const f32x4 v = acc2[mt][hh*4 + ap];
          f16x4 hv;
          hv[0]=(f16)fmaxf(v[0],0.f); hv[1]=(f16)fmaxf(v[1],0.f);
          hv[2]=(f16)fmaxf(v[2],0.f); hv[3]=(f16)fmaxf(v[3],0.f);
          *(f16x4*)&sm[hb + r15*72 + ap*16 + g*4] = hv;
        }
        #pragma unroll
        for (int sl = 0; sl < 2; ++sl)
          B3[mt][hh*2 + sl] = *(const f16x8*)&sm[hb + r15*72 + sl*32 + g*8];
      }

    // issue next tile's ea loads (covered by layer 3 + store)
    issueEA(t1);

    // ---- layer 3 (swapped): n3=64, K=128 ----
    f32x4 acc3[2][4];
    #pragma unroll
    for (int a = 0; a < 4; ++a) {
      const f32x4 bv = *(const f32x4*)&bias[256 + a*16 + g*4];
      acc3[0][a] = bv; acc3[1][a] = bv;
    }
    #pragma unroll
    for (int s = 0; s < 4; ++s)
      #pragma unroll
      for (int a = 0; a < 4; ++a) {
        const f16x8 wf = *(const f16x8*)&sm[EW3_OFF + (a*16 + r15)*136 + s*32 + g*8];
        acc3[0][a] = MFMA16(wf, B3[0][s], acc3[0][a]);
        acc3[1][a] = MFMA16(wf, B3[1][s], acc3[1][a]);
      }

    // ---- epilogue: vector stores (lane holds e[m][16a+4g .. +3]) ----
    const int base = tile * 256 + w * 32;
    #pragma unroll
    for (int mt = 0; mt < 2; ++mt) {
      const int m = base + mt * 16 + r15;
      #pragma unroll
      for (int a = 0; a < 4; ++a)
        *(f32x4*)&e_out[(size_t)m * 64 + a*16 + g*4] = acc3[mt][a];
    }

    #pragma unroll
    for (int mt = 0; mt < 2; ++mt) { rC[mt] = rN[mt]; cC[mt] = cN[mt]; bC[mt] = bN[mt]; }
  }
}

// ---------------- e scatter-add: contiguous read + row-coalesced f32 atomics ----------------
// Replaces scan+fill+nsum. Wave reads 4 edge rows (4x256B contiguous) and fires
// atomicAdds; all 64 lanes of one op target one 256B n_sum row (dense cachelines).
__global__ void escatter_kernel(const float* __restrict__ e_src, const int* __restrict__ ei,
                                float* __restrict__ n_sum) {
  const int l = threadIdx.x & 63;
  const int wid = (blockIdx.x * blockDim.x + threadIdx.x) >> 6;
  const int nw = (gridDim.x * blockDim.x) >> 6;
  for (int base = wid * 4; base < EE; base += nw * 4) {
    float v[4]; int r[4];
    #pragma unroll
    for (int k = 0; k < 4; ++k) {
      v[k] = e_src[(size_t)(base + k) * 64 + l];
      r[k] = ei[base + k];
    }
    #pragma unroll
    for (int k = 0; k < 4; ++k)
      atomicAdd(&n_sum[(size_t)r[k] * 64 + l], v[k]);
  }
}

// ---------------- node MLP (persistent) ----------------
__global__ __launch_bounds__(256, 1) void node_mlp_kernel(
    const float* __restrict__ x, const float* __restrict__ u,
    const int* __restrict__ batch, const float* __restrict__ n_sum,
    const int* __restrict__ deg,
    const f16* __restrict__ w1t, const f16* __restrict__ w2t, const f16* __restrict__ w3t,
    const float* __restrict__ b1, const float* __restrict__ b2, const float* __restrict__ b3,
    float* __restrict__ xn_out)
{
  __shared__ __align__(16) f16 sm[NLDS];
  const int t = threadIdx.x;
  for (int c = t; c < 3072; c += 256) { int r = c / 24, kc = c - r * 24;
    *(uint4*)&sm[NW1_OFF + r*NW1_RL + kc*8] = *(const uint4*)&w1t[r*192 + kc*8]; }
  for (int c = t; c < 2048; c += 256) { int r = c >> 4, kc = c & 15;
    *(uint4*)&sm[NW2_OFF + r*136 + kc*8] = *(const uint4*)&w2t[r*128 + kc*8]; }
  for (int c = t; c < 1024; c += 256) { int r = c >> 4, kc = c & 15;
    *(uint4*)&sm[NW3_OFF + r*136 + kc*8] = *(const uint4*)&w3t[r*128 + kc*8]; }
  float* bias = (float*)&sm[NB_OFF];
  if (t < 128) { bias[t] = b1[t]; bias[128 + t] = b2[t]; }
  if (t < 64)  { bias[256 + t] = b3[t]; }
  __syncthreads();

  const int l = t & 63, w = t >> 6;
  const int r15 = l & 15, g = l >> 4;
  const int hb = NH_OFF + w * (32 * 136);
  const int NTT = (NN + 127) / 128;   // 391

  for (int tile = blockIdx.x; tile < NTT; tile += gridDim.x) {
    const int base = tile * 128 + w * 32;
    f16x8 A1[2][6];
    #pragma unroll
    for (int mt = 0; mt < 2; ++mt) {
      int raw = base + mt * 16 + r15;
      int node = raw < NN ? raw : NN - 1;
      float inv = 1.0f / fmaxf((float)deg[node], 1.0f);
      const float* sA = n_sum + (size_t)node * 64;
      const float* sB = x + (size_t)node * 64;
      const float* sC = u + (size_t)batch[node] * 64;
      #pragma unroll
      for (int s = 0; s < 6; ++s) {
        const int off = (s & 1) * 32 + g * 8;
        if (s < 2)      A1[mt][s] = pack8s(sA + off, inv);
        else if (s < 4) A1[mt][s] = pack8(sB + off);
        else            A1[mt][s] = pack8(sC + off);
      }
    }
    f32x4 acc3[2][4];
    mlp3_core<6, NW1_RL, NW1_OFF, NW2_OFF, NW3_OFF>(sm, bias, bias + 128, bias + 256,
                                                    A1, hb, r15, g, acc3);
    #pragma unroll
    for (int mt = 0; mt < 2; ++mt)
      #pragma unroll
      for (int nt = 0; nt < 4; ++nt)
        #pragma unroll
        for (int i = 0; i < 4; ++i) {
          const int m = base + mt * 16 + g * 4 + i;
          if (m < NN) xn_out[(size_t)m * 64 + nt * 16 + r15] = acc3[mt][nt][i];
        }
  }
}

// ---------------- per-batch segmented sums ----------------
__global__ void batch_sum_kernel(const float* __restrict__ xn, const float* __restrict__ n_sum,
                                 const int* __restrict__ deg, const int* __restrict__ bstart,
                                 float* __restrict__ nbsum, float* __restrict__ ebsum,
                                 int* __restrict__ ncnt, int* __restrict__ ecnt) {
  __shared__ float red0[256];
  __shared__ float red1[256];
  __shared__ int   redi[256];
  const int b = blockIdx.x;
  const int s = bstart[b], e = bstart[b + 1];
  const int t = threadIdx.x, c = t & 63, j0 = t >> 6;
  float xs = 0.f, ns = 0.f; int dc = 0;
  for (int j = s + j0; j < e; j += 4) {
    xs += xn[(size_t)j * 64 + c];
    ns += n_sum[(size_t)j * 64 + c];
    if (c == 0) dc += deg[j];
  }
  red0[t] = xs; red1[t] = ns; redi[t] = dc;
  __syncthreads();
  if (t < 128) { red0[t] += red0[t + 128]; red1[t] += red1[t + 128]; redi[t] += redi[t + 128]; }
  __syncthreads();
  if (t < 64) {
    float a0 = red0[t] + red0[t + 64];
    float a1 = red1[t] + red1[t + 64];
    nbsum[b * 64 + t] = a0;
    ebsum[b * 64 + t] = a1;
    if (t == 0) { ncnt[b] = e - s; ecnt[b] = redi[0] + redi[64]; }
  }
}

// ---------------- global MLP ----------------
__global__ __launch_bounds__(256, 1) void global_mlp_kernel(
    const float* __restrict__ u, const float* __restrict__ nbsum,
    const float* __restrict__ ebsum, const int* __restrict__ ncnt,
    const int* __restrict__ ecnt,
    const f16* __restrict__ w1t, const f16* __restrict__ w2t, const f16* __restrict__ w3t,
    const float* __restrict__ b1, const float* __restrict__ b2, const float* __restrict__ b3,
    float* __restrict__ un_out)
{
  __shared__ __align__(16) f16 sm[NLDS];
  const int t = threadIdx.x;
  for (int c = t; c < 3072; c += 256) { int r = c / 24, kc = c - r * 24;
    *(uint4*)&sm[NW1_OFF + r*NW1_RL + kc*8] = *(const uint4*)&w1t[r*192 + kc*8]; }
  for (int c = t; c < 2048; c += 256) { int r = c >> 4, kc = c & 15;
    *(uint4*)&sm[NW2_OFF + r*136 + kc*8] = *(const uint4*)&w2t[r*128 + kc*8]; }
  for (int c = t; c < 1024; c += 256) { int r = c >> 4, kc = c & 15;
    *(uint4*)&sm[NW3_OFF + r*136 + kc*8] = *(const uint4*)&w3t[r*128 + kc*8]; }
  float* bias = (float*)&sm[NB_OFF];
  if (t < 128) { bias[t] = b1[t]; bias[128 + t] = b2[t]; }
  if (t < 64)  { bias[256 + t] = b3[t]; }
  __syncthreads();

  const int l = t & 63, w = t >> 6;
  const int r15 = l & 15, g = l >> 4;
  const int hb = NH_OFF + w * (32 * 136);
  const int base = blockIdx.x * 128 + w * 32;

  f16x8 A1[2][6];
  #pragma unroll
  for (int mt = 0; mt < 2; ++mt) {
    const int r = base + mt * 16 + r15;
    const float invn = 1.0f / fmaxf((float)ncnt[r], 1.0f);
    const float inve = 1.0f / fmaxf((float)ecnt[r], 1.0f);
    const float* sA = u + (size_t)r * 64;
    const float* sB = nbsum + (size_t)r * 64;
    const float* sC = ebsum + (size_t)r * 64;
    #pragma unroll
    for (int s = 0; s < 6; ++s) {
      const int off = (s & 1) * 32 + g * 8;
      if (s < 2)      A1[mt][s] = pack8(sA + off);
      else if (s < 4) A1[mt][s] = pack8s(sB + off, invn);
      else            A1[mt][s] = pack8s(sC + off, inve);
    }
  }
  f32x4 acc3[2][4];
  mlp3_core<6, NW1_RL, NW1_OFF, NW2_OFF, NW3_OFF>(sm, bias, bias + 128, bias + 256,
                                                  A1, hb, r15, g, acc3);
  #pragma unroll
  for (int mt = 0; mt < 2; ++mt)
    #pragma unroll
    for (int nt = 0; nt < 4; ++nt)
      #pragma unroll
      for (int i = 0; i < 4; ++i) {
        const int m = base + mt * 16 + g * 4 + i;
        un_out[(size_t)m * 64 + nt * 16 + r15] = acc3[mt][nt][i];
      }
}

// ---------------- host launcher ----------------
extern "C" void kernel_launch(void* const* d_in, const int* in_sizes, int n_in,
                              void* d_out, int out_size, void* d_ws, size_t ws_size,
                              hipStream_t stream)
{
  (void)in_sizes; (void)n_in; (void)out_size; (void)ws_size;
  const float* x     = (const float*)d_in[0];
  const float* ea    = (const float*)d_in[1];
  const float* u     = (const float*)d_in[2];
  const int*   ei    = (const int*)d_in[3];
  const int*   batch = (const int*)d_in[4];
  const float* ew1 = (const float*)d_in[5];  const float* eb1 = (const float*)d_in[6];
  const float* ew2 = (const float*)d_in[7];  const float* eb2 = (const float*)d_in[8];
  const float* ew3 = (const float*)d_in[9];  const float* eb3 = (const float*)d_in[10];
  const float* nw1 = (const float*)d_in[11]; const float* nb1 = (const float*)d_in[12];
  const float* nw2 = (const float*)d_in[13]; const float* nb2 = (const float*)d_in[14];
  const float* nw3 = (const float*)d_in[15]; const float* nb3 = (const float*)d_in[16];
  const float* gw1 = (const float*)d_in[17]; const float* gb1 = (const float*)d_in[18];
  const float* gw2 = (const float*)d_in[19]; const float* gb2 = (const float*)d_in[20];
  const float* gw3 = (const float*)d_in[21]; const float* gb3 = (const float*)d_in[22];

  float* xn_out = (float*)d_out;
  float* e_out  = xn_out + (size_t)NN * DD;
  float* un_out = e_out + (size_t)EE * DD;

  char* p = (char*)d_ws;
  auto alloc = [&](size_t bytes) -> void* {
    void* r = (void*)p; p += (bytes + 255) & ~(size_t)255; return r;
  };
  // NOTE: 9 weight buffers must stay contiguous in this order (prep writes linearly)
  f16* wtE1 = (f16*)alloc(256 * 128 * 2);
  f16* wtE2 = (f16*)alloc(128 * 128 * 2);
  f16* wtE3 = (f16*)alloc(128 * 64 * 2);
  f16* wtN1 = (f16*)alloc(192 * 128 * 2);
  f16* wtN2 = (f16*)alloc(128 * 128 * 2);
  f16* wtN3 = (f16*)alloc(128 * 64 * 2);
  f16* wtG1 = (f16*)alloc(192 * 128 * 2);
  f16* wtG2 = (f16*)alloc(128 * 128 * 2);
  f16* wtG3 = (f16*)alloc(128 * 64 * 2);
  int* deg    = (int*)alloc((size_t)NN * 4);
  int* bstart = (int*)alloc((size_t)(BBATCH + 1) * 4);
  float* nbsum = (float*)alloc((size_t)BBATCH * 64 * 4);
  float* ebsum = (float*)alloc((size_t)BBATCH * 64 * 4);
  int* ncnt = (int*)alloc((size_t)BBATCH * 4);
  int* ecnt = (int*)alloc((size_t)BBATCH * 4);
  float* n_sum = (float*)alloc((size_t)NN * 64 * 4);
  f16* xh = (f16*)alloc((size_t)NN * 64 * 2);
  f16* uh = (f16*)alloc((size_t)BBATCH * 64 * 2);

  hipMemsetAsync(deg, 0, (size_t)NN * 4, stream);
  hipMemsetAsync(n_sum, 0, (size_t)NN * 64 * 4, stream);
  prep_kernel<<<dim3(6250), dim3(256), 0, stream>>>(
      ew1, ew2, ew3, nw1, nw2, nw3, gw1, gw2, gw3, wtE1,
      x, u, xh, uh, ei, deg, batch, bstart);

  edge_mlp_kernel<<<dim3(256), dim3(512), 0, stream>>>(
      xh, ea, uh, ei, batch, wtE1, wtE2, wtE3, eb1, eb2, eb3, e_out);

  escatter_kernel<<<dim3(4096), dim3(256), 0, stream>>>(e_out, ei, n_sum);

  node_mlp_kernel<<<dim3(256), dim3(256), 0, stream>>>(
      x, u, batch, n_sum, deg, wtN1, wtN2, wtN3, nb1, nb2, nb3, xn_out);

  batch_sum_kernel<<<dim3(BBATCH), dim3(256), 0, stream>>>(
      xn_out, n_sum, deg, bstart, nbsum, ebsum, ncnt, ecnt);

  global_mlp_kernel<<<dim3(2), dim3(256), 0, stream>>>(
      u, nbsum, ebsum, ncnt, ecnt, wtG1, wtG2, wtG3, gb1, gb2, gb3, un_out);
}